// Round 2
// baseline (29901.697 us; speedup 1.0000x reference)
//
#include <hip/hip_runtime.h>
#include <hip/hip_bf16.h>
#include <math.h>

#define B_   128
#define HW_  224
#define P_   16
#define D_   512
#define NH_  8
#define L_   6
#define M_   2048
#define NC_  10
#define GP_  14
#define T_   197
#define TP_  208    // padded T (K-dim of PV gemm, lda of S/P)
#define EPS_ 1e-5f
#define CHUNK_ 6304  // BT/4 for MLP chunking

typedef __hip_bfloat16 bf16;
typedef __attribute__((ext_vector_type(8))) __bf16 bf16x8;
typedef __attribute__((ext_vector_type(4))) float  f32x4;

// ---------------- elementwise helpers ----------------

__global__ void k_f32_to_bf16(const float* __restrict__ in, bf16* __restrict__ out, long n) {
    long stride = (long)gridDim.x * blockDim.x;
    for (long i = (long)blockIdx.x * blockDim.x + threadIdx.x; i < n; i += stride)
        out[i] = __float2bfloat16(in[i]);
}

__global__ void k_patchify(const float* __restrict__ img, bf16* __restrict__ patches) {
    long idx = (long)blockIdx.x * blockDim.x + threadIdx.x;
    long total = (long)B_ * 196 * 256;
    if (idx >= total) return;
    int q = (int)(idx & 255);
    int p = (int)((idx >> 8) % 196);
    int b = (int)(idx / (196 * 256));
    int gy = p / GP_, gx = p % GP_;
    int py = q >> 4,  px = q & 15;
    patches[idx] = __float2bfloat16(img[((long)b * HW_ + gy * P_ + py) * HW_ + gx * P_ + px]);
}

__global__ void k_cls_token(const float* __restrict__ tok, float* __restrict__ x) {
    int i = blockIdx.x * blockDim.x + threadIdx.x;
    if (i < B_ * D_) {
        int b = i >> 9, d = i & 511;
        x[(long)b * T_ * D_ + d] = tok[d];
    }
}

// ---------------- LayerNorm (one wave per row of 512) ----------------
// WRITE_Y: also write f32 normalized value to `of` (may alias x — in-place).

template<int WRITE_Y>
__global__ __launch_bounds__(256) void k_ln(const float* x,
        const float* __restrict__ g, const float* __restrict__ bb,
        bf16* __restrict__ obf, float* of, int rows) {
    int wid = blockIdx.x * 4 + (threadIdx.x >> 6);
    if (wid >= rows) return;
    int lane = threadIdx.x & 63;
    const float* xr = x + (long)wid * D_;
    float v[8];
    float s = 0.f;
#pragma unroll
    for (int i = 0; i < 8; i++) { v[i] = xr[i * 64 + lane]; s += v[i]; }
#pragma unroll
    for (int off = 32; off; off >>= 1) s += __shfl_xor(s, off, 64);
    float mean = s * (1.f / D_);
    float sq = 0.f;
#pragma unroll
    for (int i = 0; i < 8; i++) { float d = v[i] - mean; sq += d * d; }
#pragma unroll
    for (int off = 32; off; off >>= 1) sq += __shfl_xor(sq, off, 64);
    float inv = rsqrtf(sq * (1.f / D_) + EPS_);
#pragma unroll
    for (int i = 0; i < 8; i++) {
        int d = i * 64 + lane;
        float val = (v[i] - mean) * inv * g[d] + bb[d];
        obf[(long)wid * D_ + d] = __float2bfloat16(val);
        if (WRITE_Y) of[(long)wid * D_ + d] = val;
    }
}

// ---------------- row softmax: S (f32, lda=TP_) -> P (bf16, lda=TP_) ----------------

__global__ __launch_bounds__(256) void k_softmax(const float* __restrict__ S,
        bf16* __restrict__ Pm, int rows, float scale) {
    int wid = blockIdx.x * 4 + (threadIdx.x >> 6);
    if (wid >= rows) return;
    int lane = threadIdx.x & 63;
    const float* sr = S + (long)wid * TP_;
    bf16* pr = Pm + (long)wid * TP_;
    float v[4];
    float mx = -1e30f;
#pragma unroll
    for (int i = 0; i < 4; i++) {
        int c = i * 64 + lane;
        v[i] = (c < T_) ? sr[c] * scale : -1e30f;
        mx = fmaxf(mx, v[i]);
    }
#pragma unroll
    for (int off = 32; off; off >>= 1) mx = fmaxf(mx, __shfl_xor(mx, off, 64));
    float sum = 0.f;
#pragma unroll
    for (int i = 0; i < 4; i++) {
        int c = i * 64 + lane;
        float e = (c < T_) ? expf(v[i] - mx) : 0.f;
        v[i] = e; sum += e;
    }
#pragma unroll
    for (int off = 32; off; off >>= 1) sum += __shfl_xor(sum, off, 64);
    float inv = 1.f / sum;
#pragma unroll
    for (int i = 0; i < 4; i++) {
        int c = i * 64 + lane;
        if (c < TP_) pr[c] = __float2bfloat16((c < T_) ? v[i] * inv : 0.f);
    }
}

// ---------------- GEMM helpers ----------------

__device__ __forceinline__ float geluf(float v) {
    return 0.5f * v * (1.f + erff(v * 0.70710678118654752f));
}

// C[M,N] = A[M,K] @ B[N,K]^T.  K % 32 == 0.  128x128 tile, 4 waves of 64x64.
// MODE 0: f32 store (v + bias?)       MODE 1: bf16 store (v + bias)
// MODE 2: bf16 store gelu(v + bias)   MODE 3: f32 store (v + bias + res)  (res may alias C)
template<int MODE>
__global__ __launch_bounds__(256) void k_gemm_bt(
        const bf16* __restrict__ A, long lda, long bsA,
        const bf16* __restrict__ Bw, long ldb, long bsB,
        void* __restrict__ Cp, long ldc, long bsC,
        const float* __restrict__ bias,
        const float* res, long ldres,
        int Mt, int Nt, int Kt) {
    __shared__ __align__(16) bf16 As[128][32];
    __shared__ __align__(16) bf16 Bs[128][32];
    int bz = blockIdx.z;
    A  += (long)bz * bsA;
    Bw += (long)bz * bsB;
    int m0 = blockIdx.y * 128, n0 = blockIdx.x * 128;
    int tid = threadIdx.x;
    int wv = tid >> 6, lane = tid & 63;
    int wm = (wv >> 1) * 64, wn = (wv & 1) * 64;
    int lrow = lane & 15, koff = (lane >> 4) * 8;

    f32x4 acc[4][4];
#pragma unroll
    for (int i = 0; i < 4; i++)
#pragma unroll
        for (int j = 0; j < 4; j++) acc[i][j] = (f32x4){0.f, 0.f, 0.f, 0.f};

    int kTiles = Kt >> 5;
    for (int kt = 0; kt < kTiles; kt++) {
        int k0 = kt << 5;
#pragma unroll
        for (int i = 0; i < 2; i++) {
            int s = i * 256 + tid;
            int r = s >> 2, pp = (s & 3) * 8;
            uint4 va = make_uint4(0u, 0u, 0u, 0u);
            if (m0 + r < Mt) va = *(const uint4*)(A + (long)(m0 + r) * lda + k0 + pp);
            *(uint4*)&As[r][pp] = va;
            uint4 vb = make_uint4(0u, 0u, 0u, 0u);
            if (n0 + r < Nt) vb = *(const uint4*)(Bw + (long)(n0 + r) * ldb + k0 + pp);
            *(uint4*)&Bs[r][pp] = vb;
        }
        __syncthreads();
        bf16x8 af[4], bfr[4];
#pragma unroll
        for (int mi = 0; mi < 4; mi++) af[mi]  = *(const bf16x8*)&As[wm + mi * 16 + lrow][koff];
#pragma unroll
        for (int ni = 0; ni < 4; ni++) bfr[ni] = *(const bf16x8*)&Bs[wn + ni * 16 + lrow][koff];
#pragma unroll
        for (int mi = 0; mi < 4; mi++)
#pragma unroll
            for (int ni = 0; ni < 4; ni++)
                acc[mi][ni] = __builtin_amdgcn_mfma_f32_16x16x32_bf16(af[mi], bfr[ni], acc[mi][ni], 0, 0, 0);
        __syncthreads();
    }

    int r4 = (lane >> 4) * 4, c1 = lane & 15;
#pragma unroll
    for (int mi = 0; mi < 4; mi++) {
#pragma unroll
        for (int r = 0; r < 4; r++) {
            int row = m0 + wm + mi * 16 + r4 + r;
            if (row >= Mt) continue;
#pragma unroll
            for (int ni = 0; ni < 4; ni++) {
                int col = n0 + wn + ni * 16 + c1;
                if (col >= Nt) continue;
                float v = acc[mi][ni][r];
                if (bias) v += bias[col];
                long cidx = (long)bz * bsC + (long)row * ldc + col;
                if (MODE == 0)      ((float*)Cp)[cidx] = v;
                else if (MODE == 1) ((bf16*)Cp)[cidx]  = __float2bfloat16(v);
                else if (MODE == 2) ((bf16*)Cp)[cidx]  = __float2bfloat16(geluf(v));
                else                ((float*)Cp)[cidx] = v + res[(long)row * ldres + col];
            }
        }
    }
}

// C[M,N] (op)= A[M,K] @ B[K,N], B row-major KxN. Ragged K ok (zero-filled).
// MODE 0: bf16 store.   MODE 1: f32 accumulate C += v + rowbias[row] (rowbias optional)
template<int MODE>
__global__ __launch_bounds__(256) void k_gemm_nn(
        const bf16* __restrict__ A, long lda, long bsA,
        const bf16* __restrict__ Bw, long ldb, long bsB,
        void* __restrict__ Cp, long ldc, long bsC,
        const float* __restrict__ rowbias,
        int Mt, int Nt, int Kt) {
    __shared__ __align__(16) bf16 As[128][32];
    __shared__ __align__(16) bf16 Bs[128][32];
    int bz = blockIdx.z;
    A  += (long)bz * bsA;
    Bw += (long)bz * bsB;
    int m0 = blockIdx.y * 128, n0 = blockIdx.x * 128;
    int tid = threadIdx.x;
    int wv = tid >> 6, lane = tid & 63;
    int wm = (wv >> 1) * 64, wn = (wv & 1) * 64;
    int lrow = lane & 15, koff = (lane >> 4) * 8;
    const bf16 zv = __float2bfloat16(0.f);

    f32x4 acc[4][4];
#pragma unroll
    for (int i = 0; i < 4; i++)
#pragma unroll
        for (int j = 0; j < 4; j++) acc[i][j] = (f32x4){0.f, 0.f, 0.f, 0.f};

    int kTiles = (Kt + 31) >> 5;
    for (int kt = 0; kt < kTiles; kt++) {
        int k0 = kt << 5;
#pragma unroll
        for (int i = 0; i < 16; i++) {          // A: [128 rows][32 k] scalar
            int s = i * 256 + tid;
            int r = s >> 5, k = s & 31;
            bf16 v = zv;
            if (m0 + r < Mt && k0 + k < Kt) v = A[(long)(m0 + r) * lda + k0 + k];
            As[r][k] = v;
        }
#pragma unroll
        for (int i = 0; i < 16; i++) {          // B: transpose into Bs[n][k]
            int s = i * 256 + tid;
            int k = s >> 7, n = s & 127;
            bf16 v = zv;
            if (k0 + k < Kt && n0 + n < Nt) v = Bw[(long)(k0 + k) * ldb + n0 + n];
            Bs[n][k] = v;
        }
        __syncthreads();
        bf16x8 af[4], bfr[4];
#pragma unroll
        for (int mi = 0; mi < 4; mi++) af[mi]  = *(const bf16x8*)&As[wm + mi * 16 + lrow][koff];
#pragma unroll
        for (int ni = 0; ni < 4; ni++) bfr[ni] = *(const bf16x8*)&Bs[wn + ni * 16 + lrow][koff];
#pragma unroll
        for (int mi = 0; mi < 4; mi++)
#pragma unroll
            for (int ni = 0; ni < 4; ni++)
                acc[mi][ni] = __builtin_amdgcn_mfma_f32_16x16x32_bf16(af[mi], bfr[ni], acc[mi][ni], 0, 0, 0);
        __syncthreads();
    }

    int r4 = (lane >> 4) * 4, c1 = lane & 15;
#pragma unroll
    for (int mi = 0; mi < 4; mi++) {
#pragma unroll
        for (int r = 0; r < 4; r++) {
            int row = m0 + wm + mi * 16 + r4 + r;
            if (row >= Mt) continue;
#pragma unroll
            for (int ni = 0; ni < 4; ni++) {
                int col = n0 + wn + ni * 16 + c1;
                if (col >= Nt) continue;
                float v = acc[mi][ni][r];
                long cidx = (long)bz * bsC + (long)row * ldc + col;
                if (MODE == 0) {
                    ((bf16*)Cp)[cidx] = __float2bfloat16(v);
                } else {
                    if (rowbias) v += rowbias[row];
                    ((float*)Cp)[cidx] += v;
                }
            }
        }
    }
}

// ---------------- classifier + softmax ----------------

__global__ __launch_bounds__(64) void k_classifier(const float* __restrict__ x,
        const float* __restrict__ w, const float* __restrict__ bias, float* __restrict__ out) {
    int b = blockIdx.x, lane = threadIdx.x;
    const float* xr = x + (long)b * T_ * D_;   // row 0 = cls token
    float logits[NC_];
#pragma unroll
    for (int c = 0; c < NC_; c++) {
        float s = 0.f;
        for (int d = lane; d < D_; d += 64) s += xr[d] * w[c * D_ + d];
#pragma unroll
        for (int off = 32; off; off >>= 1) s += __shfl_xor(s, off, 64);
        logits[c] = s + bias[c];
    }
    float mx = -1e30f;
#pragma unroll
    for (int c = 0; c < NC_; c++) mx = fmaxf(mx, logits[c]);
    float sum = 0.f;
#pragma unroll
    for (int c = 0; c < NC_; c++) { float e = expf(logits[c] - mx); logits[c] = e; sum += e; }
    if (lane == 0) {
        float inv = 1.f / sum;
#pragma unroll
        for (int c = 0; c < NC_; c++) out[(long)b * NC_ + c] = logits[c] * inv;
    }
}

// ---------------- host ----------------

extern "C" void kernel_launch(void* const* d_in, const int* in_sizes, int n_in,
                              void* d_out, int out_size, void* d_ws, size_t ws_size,
                              hipStream_t stream) {
    const float* images  = (const float*)d_in[0];
    const float* lin_w   = (const float*)d_in[1];
    const float* lin_b   = (const float*)d_in[2];
    const float* cls_tok = (const float*)d_in[3];
    const float* ln1_g   = (const float*)d_in[4];
    const float* ln1_b   = (const float*)d_in[5];
    const float* ln2_g   = (const float*)d_in[6];
    const float* ln2_b   = (const float*)d_in[7];
    const float* qw      = (const float*)d_in[8];
    const float* qb      = (const float*)d_in[9];
    const float* kw      = (const float*)d_in[10];
    const float* kb      = (const float*)d_in[11];
    const float* vw      = (const float*)d_in[12];
    const float* vb      = (const float*)d_in[13];
    const float* map_w   = (const float*)d_in[14];
    const float* map_b   = (const float*)d_in[15];
    const float* w1      = (const float*)d_in[16];
    const float* b1      = (const float*)d_in[17];
    const float* w2      = (const float*)d_in[18];
    const float* b2      = (const float*)d_in[19];
    const float* cls_w   = (const float*)d_in[20];
    const float* cls_b   = (const float*)d_in[21];

    char* wp = (char*)d_ws;
    auto alloc = [&](size_t bytes) { char* p = wp; wp += (bytes + 255) & ~(size_t)255; return p; };
    const long BT = (long)B_ * T_;                       // 25216

    // Slim workspace plan (~204 MB total):
    float* xf  = (float*)alloc(BT * D_ * 4);             // x (and y in-place after LN2)
    bf16*  hb  = (bf16*) alloc(BT * D_ * 2);             // LN1/LN2 bf16 output
    bf16*  Qh  = (bf16*) alloc(BT * D_ * 2);             // Q, then V
    bf16*  Kh  = (bf16*) alloc(BT * D_ * 2);             // K, then av
    float* Sb  = (float*)alloc((long)B_ * T_ * TP_ * 4);
    bf16*  Pb  = (bf16*) alloc((long)B_ * T_ * TP_ * 2);
    bf16*  m1c = (bf16*) alloc((long)CHUNK_ * M_ * 2);   // MLP hidden, chunked
    bf16*  patches = m1c;                                // alias: only used pre-layer0
    bf16*  wq  = (bf16*)alloc((long)NH_ * D_ * D_ * 2);  // per-layer weight staging
    bf16*  wk  = (bf16*)alloc((long)NH_ * D_ * D_ * 2);
    bf16*  wv  = (bf16*)alloc((long)NH_ * D_ * D_ * 2);
    bf16*  wmap= (bf16*)alloc((long)T_ * T_ * NH_ * 2);
    bf16*  w1l = (bf16*)alloc((long)M_ * D_ * 2);
    bf16*  w2l = (bf16*)alloc((long)D_ * M_ * 2);
    bf16*  wlin= (bf16*)alloc((long)D_ * 256 * 2);

    auto conv = [&](const float* src, bf16* dst, long n) {
        k_f32_to_bf16<<<1024, 256, 0, stream>>>(src, dst, n);
    };

    conv(lin_w, wlin, (long)D_ * 256);
    {
        long tot = (long)B_ * 196 * 256;
        k_patchify<<<(int)((tot + 255) / 256), 256, 0, stream>>>(images, patches);
        k_cls_token<<<(B_ * D_ + 255) / 256, 256, 0, stream>>>(cls_tok, xf);
        // emb -> x[:,1:,:]
        k_gemm_bt<0><<<dim3(4, 2, B_), 256, 0, stream>>>(
            patches, 256, (long)196 * 256,
            wlin, 256, 0,
            xf + D_, D_, (long)T_ * D_,
            lin_b, nullptr, 0,
            196, D_, 256);
    }

    const float scale = 1.0f / 14.0f;
    const int lnGrid = (int)((BT + 3) / 4);

    for (int l = 0; l < L_; l++) {
        // stage this layer's weights in bf16
        conv(qw + (long)l * NH_ * D_ * D_, wq, (long)NH_ * D_ * D_);
        conv(kw + (long)l * NH_ * D_ * D_, wk, (long)NH_ * D_ * D_);
        conv(vw + (long)l * NH_ * D_ * D_, wv, (long)NH_ * D_ * D_);
        conv(map_w + (long)l * T_ * T_ * NH_, wmap, (long)T_ * T_ * NH_);
        conv(w1 + (long)l * M_ * D_, w1l, (long)M_ * D_);
        conv(w2 + (long)l * D_ * M_, w2l, (long)D_ * M_);

        k_ln<0><<<lnGrid, 256, 0, stream>>>(xf, ln1_g + l * D_, ln1_b + l * D_, hb, nullptr, (int)BT);

        for (int h = 0; h < NH_; h++) {
            int lh = l * NH_ + h;
            // Q -> Qh ; K -> Kh
            k_gemm_bt<1><<<dim3(4, 197, 1), 256, 0, stream>>>(
                hb, D_, 0, wq + (long)h * D_ * D_, D_, 0, Qh, D_, 0,
                qb + (long)lh * D_, nullptr, 0, (int)BT, D_, D_);
            k_gemm_bt<1><<<dim3(4, 197, 1), 256, 0, stream>>>(
                hb, D_, 0, wk + (long)h * D_ * D_, D_, 0, Kh, D_, 0,
                kb + (long)lh * D_, nullptr, 0, (int)BT, D_, D_);

            // S = Q @ K^T  (per image)
            k_gemm_bt<0><<<dim3(2, 2, B_), 256, 0, stream>>>(
                Qh, D_, (long)T_ * D_, Kh, D_, (long)T_ * D_,
                Sb, TP_, (long)T_ * TP_, nullptr, nullptr, 0, T_, T_, D_);

            k_softmax<<<lnGrid, 256, 0, stream>>>(Sb, Pb, (int)(B_ * T_), scale);

            // V -> Qh  (Q is dead after S)
            k_gemm_bt<1><<<dim3(4, 197, 1), 256, 0, stream>>>(
                hb, D_, 0, wv + (long)h * D_ * D_, D_, 0, Qh, D_, 0,
                vb + (long)lh * D_, nullptr, 0, (int)BT, D_, D_);

            // av = P @ V -> Kh  (K is dead after softmax)
            k_gemm_nn<0><<<dim3(4, 2, B_), 256, 0, stream>>>(
                Pb, TP_, (long)T_ * TP_, Qh, D_, (long)T_ * D_,
                Kh, D_, (long)T_ * D_, nullptr, T_, D_, T_);

            // x += map_w_slice @ av   (+ map_b on first head)
            k_gemm_nn<1><<<dim3(4, 2, B_), 256, 0, stream>>>(
                wmap + h * T_, (long)T_ * NH_, 0,
                Kh, D_, (long)T_ * D_,
                xf, D_, (long)T_ * D_,
                (h == 0) ? (map_b + (long)l * T_) : nullptr,
                T_, D_, T_);
        }

        // y = LN2(x): bf16 -> hb, f32 in-place over xf (x is dead)
        k_ln<1><<<lnGrid, 256, 0, stream>>>(xf, ln2_g + l * D_, ln2_b + l * D_, hb, xf, (int)BT);

        // MLP in 4 row-chunks: x = y + gelu(y@W1^T+b1)@W2^T+b2
        for (int c = 0; c < 4; c++) {
            long r0 = (long)c * CHUNK_;
            k_gemm_bt<2><<<dim3(16, (CHUNK_ + 127) / 128, 1), 256, 0, stream>>>(
                hb + r0 * D_, D_, 0, w1l, D_, 0,
                m1c, M_, 0, b1 + (long)l * M_, nullptr, 0, CHUNK_, M_, D_);
            k_gemm_bt<3><<<dim3(4, (CHUNK_ + 127) / 128, 1), 256, 0, stream>>>(
                m1c, M_, 0, w2l, M_, 0,
                xf + r0 * D_, D_, 0, b2 + (long)l * D_, xf + r0 * D_, D_, CHUNK_, D_, M_);
        }
    }

    k_classifier<<<B_, 64, 0, stream>>>(xf, cls_w, cls_b, (float*)d_out);
}

// Round 3
// 17284.494 us; speedup vs baseline: 1.7300x; 1.7300x over previous
//
#include <hip/hip_runtime.h>
#include <hip/hip_bf16.h>
#include <math.h>

#define B_   128
#define HW_  224
#define P_   16
#define D_   512
#define NH_  8
#define L_   6
#define M_   2048
#define NC_  10
#define GP_  14
#define T_   197
#define TP_  224    // padded T (multiple of 32): lda of S/P, K-dim of PV/map gemms
#define EPS_ 1e-5f
#define CHUNK_ 6400 // MLP row chunk (multiple of 128); last chunk = 6016

typedef __hip_bfloat16 bf16;
typedef __attribute__((ext_vector_type(8))) __bf16 bf16x8;
typedef __attribute__((ext_vector_type(4))) float  f32x4;

// async global->LDS, 16B per lane. LDS dest = wave-uniform base + lane*16.
__device__ __forceinline__ void gload16(const void* g, void* l) {
    __builtin_amdgcn_global_load_lds(
        (const __attribute__((address_space(1))) void*)g,
        (__attribute__((address_space(3))) void*)l, 16, 0, 0);
}

// ---------------- elementwise helpers ----------------

__global__ void k_f32_to_bf16v(const float* __restrict__ in, bf16* __restrict__ out, long n8) {
    long stride = (long)gridDim.x * blockDim.x;
    for (long i = (long)blockIdx.x * blockDim.x + threadIdx.x; i < n8; i += stride) {
        float4 a = ((const float4*)in)[i * 2], b = ((const float4*)in)[i * 2 + 1];
        union { uint4 u; bf16 h[8]; } r;
        r.h[0] = __float2bfloat16(a.x); r.h[1] = __float2bfloat16(a.y);
        r.h[2] = __float2bfloat16(a.z); r.h[3] = __float2bfloat16(a.w);
        r.h[4] = __float2bfloat16(b.x); r.h[5] = __float2bfloat16(b.y);
        r.h[6] = __float2bfloat16(b.z); r.h[7] = __float2bfloat16(b.w);
        ((uint4*)out)[i] = r.u;
    }
}

__global__ void k_patchify(const float* __restrict__ img, bf16* __restrict__ patches) {
    long idx = (long)blockIdx.x * blockDim.x + threadIdx.x;
    long total = (long)B_ * 196 * 256;
    if (idx >= total) return;
    int q = (int)(idx & 255);
    int p = (int)((idx >> 8) % 196);
    int b = (int)(idx / (196 * 256));
    int gy = p / GP_, gx = p % GP_;
    int py = q >> 4,  px = q & 15;
    patches[idx] = __float2bfloat16(img[((long)b * HW_ + gy * P_ + py) * HW_ + gx * P_ + px]);
}

__global__ void k_cls_token(const float* __restrict__ tok, float* __restrict__ x) {
    int i = blockIdx.x * blockDim.x + threadIdx.x;
    if (i < B_ * D_) {
        int b = i >> 9, d = i & 511;
        x[(long)b * T_ * D_ + d] = tok[d];
    }
}

// map_w[l] is [T][T*NH]; produce per-head zero-K-padded A: out[h][t][s] (lda=TP_)
__global__ void k_prep_map(const float* __restrict__ in, bf16* __restrict__ out) {
    int idx = blockIdx.x * blockDim.x + threadIdx.x;
    int total = NH_ * T_ * TP_;
    if (idx >= total) return;
    int s = idx % TP_;
    int t = (idx / TP_) % T_;
    int h = idx / (TP_ * T_);
    float v = (s < T_) ? in[t * (T_ * NH_) + h * T_ + s] : 0.f;
    out[idx] = __float2bfloat16(v);
}

// ---------------- LayerNorm (one wave per row of 512) ----------------

template<int WRITE_Y>
__global__ __launch_bounds__(256) void k_ln(const float* x,
        const float* __restrict__ g, const float* __restrict__ bb,
        bf16* __restrict__ obf, float* of, int rows) {
    int wid = blockIdx.x * 4 + (threadIdx.x >> 6);
    if (wid >= rows) return;
    int lane = threadIdx.x & 63;
    const float* xr = x + (long)wid * D_;
    float v[8];
    float s = 0.f;
#pragma unroll
    for (int i = 0; i < 8; i++) { v[i] = xr[i * 64 + lane]; s += v[i]; }
#pragma unroll
    for (int off = 32; off; off >>= 1) s += __shfl_xor(s, off, 64);
    float mean = s * (1.f / D_);
    float sq = 0.f;
#pragma unroll
    for (int i = 0; i < 8; i++) { float d = v[i] - mean; sq += d * d; }
#pragma unroll
    for (int off = 32; off; off >>= 1) sq += __shfl_xor(sq, off, 64);
    float inv = rsqrtf(sq * (1.f / D_) + EPS_);
#pragma unroll
    for (int i = 0; i < 8; i++) {
        int d = i * 64 + lane;
        float val = (v[i] - mean) * inv * g[d] + bb[d];
        obf[(long)wid * D_ + d] = __float2bfloat16(val);
        if (WRITE_Y) of[(long)wid * D_ + d] = val;
    }
}

// ---------------- row softmax: S (f32, lda=TP_) -> P (bf16, lda=TP_, zero-padded) ----

__global__ __launch_bounds__(256) void k_softmax(const float* __restrict__ S,
        bf16* __restrict__ Pm, int rows, float scale) {
    int wid = blockIdx.x * 4 + (threadIdx.x >> 6);
    if (wid >= rows) return;
    int lane = threadIdx.x & 63;
    const float* sr = S + (long)wid * TP_;
    bf16* pr = Pm + (long)wid * TP_;
    float v[4];
    float mx = -1e30f;
#pragma unroll
    for (int i = 0; i < 4; i++) {
        int c = i * 64 + lane;
        v[i] = (c < T_) ? sr[c] * scale : -1e30f;
        mx = fmaxf(mx, v[i]);
    }
#pragma unroll
    for (int off = 32; off; off >>= 1) mx = fmaxf(mx, __shfl_xor(mx, off, 64));
    float sum = 0.f;
#pragma unroll
    for (int i = 0; i < 4; i++) {
        int c = i * 64 + lane;
        float e = (c < T_) ? expf(v[i] - mx) : 0.f;
        v[i] = e; sum += e;
    }
#pragma unroll
    for (int off = 32; off; off >>= 1) sum += __shfl_xor(sum, off, 64);
    float inv = 1.f / sum;
#pragma unroll
    for (int i = 0; i < 4; i++) {
        int c = i * 64 + lane;
        if (c < TP_) pr[c] = __float2bfloat16((c < T_) ? v[i] * inv : 0.f);
    }
}

// ---------------- GEMM kernels ----------------

__device__ __forceinline__ float geluf(float v) {
    return 0.5f * v * (1.f + erff(v * 0.70710678118654752f));
}

// C[M,N] = A[M,K] @ B[N,K]^T.  Guard-free loads (caller guarantees overreads are
// in-bounds-of-workspace and finite); stores guarded by Mt/Nt. K % 32 == 0.
// MODE 0: f32 store (v + bias?)       MODE 1: bf16 store (v + bias)
// MODE 2: bf16 store gelu(v + bias)   MODE 3: f32 store (v + bias + res)  (res may alias C)
template<int MODE>
__global__ __launch_bounds__(256) void k_gemm_bt(
        const bf16* __restrict__ A, long lda, long bsA,
        const bf16* __restrict__ Bw, long ldb, long bsB,
        void* __restrict__ Cp, long ldc, long bsC,
        const float* __restrict__ bias,
        const float* res, long ldres,
        int Mt, int Nt, int Kt) {
    __shared__ __align__(16) bf16 As[128][32];
    __shared__ __align__(16) bf16 Bs[128][32];
    int bz = blockIdx.z;
    A  += (long)bz * bsA;
    Bw += (long)bz * bsB;
    int m0 = blockIdx.y * 128, n0 = blockIdx.x * 128;
    int tid = threadIdx.x;
    int wv = tid >> 6, lane = tid & 63;
    int wm = (wv >> 1) * 64, wn = (wv & 1) * 64;
    int lrow = lane & 15, koff = (lane >> 4) * 8;

    int rA = tid >> 2, pA = (tid & 3) * 8;          // 64 rows per 256-thread pass
    const bf16* gA0 = A  + (long)(m0 + rA) * lda + pA;
    const bf16* gA1 = A  + (long)(m0 + 64 + rA) * lda + pA;
    const bf16* gB0 = Bw + (long)(n0 + rA) * ldb + pA;
    const bf16* gB1 = Bw + (long)(n0 + 64 + rA) * ldb + pA;
    char* lA0 = (char*)As + (wv * 64) * 16;         // wave-uniform LDS bases
    char* lA1 = (char*)As + (256 + wv * 64) * 16;
    char* lB0 = (char*)Bs + (wv * 64) * 16;
    char* lB1 = (char*)Bs + (256 + wv * 64) * 16;

    f32x4 acc[4][4];
#pragma unroll
    for (int i = 0; i < 4; i++)
#pragma unroll
        for (int j = 0; j < 4; j++) acc[i][j] = (f32x4){0.f, 0.f, 0.f, 0.f};

    int kTiles = Kt >> 5;
    for (int kt = 0; kt < kTiles; kt++) {
        long k0 = (long)kt << 5;
        gload16(gA0 + k0, lA0);
        gload16(gA1 + k0, lA1);
        gload16(gB0 + k0, lB0);
        gload16(gB1 + k0, lB1);
        __syncthreads();
        bf16x8 af[4], bfr[4];
#pragma unroll
        for (int mi = 0; mi < 4; mi++) af[mi]  = *(const bf16x8*)&As[wm + mi * 16 + lrow][koff];
#pragma unroll
        for (int ni = 0; ni < 4; ni++) bfr[ni] = *(const bf16x8*)&Bs[wn + ni * 16 + lrow][koff];
#pragma unroll
        for (int mi = 0; mi < 4; mi++)
#pragma unroll
            for (int ni = 0; ni < 4; ni++)
                acc[mi][ni] = __builtin_amdgcn_mfma_f32_16x16x32_bf16(af[mi], bfr[ni], acc[mi][ni], 0, 0, 0);
        __syncthreads();
    }

    int r4 = (lane >> 4) * 4, c1 = lane & 15;
#pragma unroll
    for (int mi = 0; mi < 4; mi++) {
#pragma unroll
        for (int r = 0; r < 4; r++) {
            int row = m0 + wm + mi * 16 + r4 + r;
            if (row >= Mt) continue;
#pragma unroll
            for (int ni = 0; ni < 4; ni++) {
                int col = n0 + wn + ni * 16 + c1;
                if (col >= Nt) continue;
                float v = acc[mi][ni][r];
                if (bias) v += bias[col];
                long cidx = (long)bz * bsC + (long)row * ldc + col;
                if (MODE == 0)      ((float*)Cp)[cidx] = v;
                else if (MODE == 1) ((bf16*)Cp)[cidx]  = __float2bfloat16(v);
                else if (MODE == 2) ((bf16*)Cp)[cidx]  = __float2bfloat16(geluf(v));
                else                ((float*)Cp)[cidx] = v + res[(long)row * ldres + col];
            }
        }
    }
}

// C[M,N] (op)= A[M,K] @ B[K,N], B row-major KxN. Guard-free loads; K % 32 == 0
// (caller zero-pads the ragged K on the A side). Stores guarded.
// MODE 0: bf16 store.   MODE 1: f32 accumulate C += v + rowbias[row] (rowbias optional)
template<int MODE>
__global__ __launch_bounds__(256) void k_gemm_nn(
        const bf16* __restrict__ A, long lda, long bsA,
        const bf16* __restrict__ Bw, long ldb, long bsB,
        void* __restrict__ Cp, long ldc, long bsC,
        const float* __restrict__ rowbias,
        int Mt, int Nt, int Kt) {
    __shared__ __align__(16) bf16 As[128][32];
    __shared__ __align__(16) bf16 Bs[128][32];
    int bz = blockIdx.z;
    A  += (long)bz * bsA;
    Bw += (long)bz * bsB;
    int m0 = blockIdx.y * 128, n0 = blockIdx.x * 128;
    int tid = threadIdx.x;
    int wv = tid >> 6, lane = tid & 63;
    int wm = (wv >> 1) * 64, wn = (wv & 1) * 64;
    int lrow = lane & 15, koff = (lane >> 4) * 8;

    int rA = tid >> 2, pA = (tid & 3) * 8;
    const bf16* gA0 = A + (long)(m0 + rA) * lda + pA;
    const bf16* gA1 = A + (long)(m0 + 64 + rA) * lda + pA;
    char* lA0 = (char*)As + (wv * 64) * 16;
    char* lA1 = (char*)As + (256 + wv * 64) * 16;
    int bk = tid & 31, bg = tid >> 5;               // B transpose staging coords

    f32x4 acc[4][4];
#pragma unroll
    for (int i = 0; i < 4; i++)
#pragma unroll
        for (int j = 0; j < 4; j++) acc[i][j] = (f32x4){0.f, 0.f, 0.f, 0.f};

    int kTiles = Kt >> 5;
    for (int kt = 0; kt < kTiles; kt++) {
        long k0 = (long)kt << 5;
        gload16(gA0 + k0, lA0);
        gload16(gA1 + k0, lA1);
#pragma unroll
        for (int i = 0; i < 2; i++) {
            int g = bg + 8 * i;
            uint4 v = *(const uint4*)(Bw + (k0 + bk) * ldb + n0 + g * 8);
            const bf16* pv = (const bf16*)&v;
#pragma unroll
            for (int j = 0; j < 8; j++) Bs[g * 8 + j][bk] = pv[j];
        }
        __syncthreads();
        bf16x8 af[4], bfr[4];
#pragma unroll
        for (int mi = 0; mi < 4; mi++) af[mi]  = *(const bf16x8*)&As[wm + mi * 16 + lrow][koff];
#pragma unroll
        for (int ni = 0; ni < 4; ni++) bfr[ni] = *(const bf16x8*)&Bs[wn + ni * 16 + lrow][koff];
#pragma unroll
        for (int mi = 0; mi < 4; mi++)
#pragma unroll
            for (int ni = 0; ni < 4; ni++)
                acc[mi][ni] = __builtin_amdgcn_mfma_f32_16x16x32_bf16(af[mi], bfr[ni], acc[mi][ni], 0, 0, 0);
        __syncthreads();
    }

    int r4 = (lane >> 4) * 4, c1 = lane & 15;
#pragma unroll
    for (int mi = 0; mi < 4; mi++) {
#pragma unroll
        for (int r = 0; r < 4; r++) {
            int row = m0 + wm + mi * 16 + r4 + r;
            if (row >= Mt) continue;
#pragma unroll
            for (int ni = 0; ni < 4; ni++) {
                int col = n0 + wn + ni * 16 + c1;
                if (col >= Nt) continue;
                float v = acc[mi][ni][r];
                long cidx = (long)bz * bsC + (long)row * ldc + col;
                if (MODE == 0) {
                    ((bf16*)Cp)[cidx] = __float2bfloat16(v);
                } else {
                    if (rowbias) v += rowbias[row];
                    ((float*)Cp)[cidx] += v;
                }
            }
        }
    }
}

// ---------------- classifier + softmax ----------------

__global__ __launch_bounds__(64) void k_classifier(const float* __restrict__ x,
        const float* __restrict__ w, const float* __restrict__ bias, float* __restrict__ out) {
    int b = blockIdx.x, lane = threadIdx.x;
    const float* xr = x + (long)b * T_ * D_;   // row 0 = cls token
    float logits[NC_];
#pragma unroll
    for (int c = 0; c < NC_; c++) {
        float s = 0.f;
        for (int d = lane; d < D_; d += 64) s += xr[d] * w[c * D_ + d];
#pragma unroll
        for (int off = 32; off; off >>= 1) s += __shfl_xor(s, off, 64);
        logits[c] = s + bias[c];
    }
    float mx = -1e30f;
#pragma unroll
    for (int c = 0; c < NC_; c++) mx = fmaxf(mx, logits[c]);
    float sum = 0.f;
#pragma unroll
    for (int c = 0; c < NC_; c++) { float e = expf(logits[c] - mx); logits[c] = e; sum += e; }
    if (lane == 0) {
        float inv = 1.f / sum;
#pragma unroll
        for (int c = 0; c < NC_; c++) out[(long)b * NC_ + c] = logits[c] * inv;
    }
}

// ---------------- host ----------------

extern "C" void kernel_launch(void* const* d_in, const int* in_sizes, int n_in,
                              void* d_out, int out_size, void* d_ws, size_t ws_size,
                              hipStream_t stream) {
    const float* images  = (const float*)d_in[0];
    const float* lin_w   = (const float*)d_in[1];
    const float* lin_b   = (const float*)d_in[2];
    const float* cls_tok = (const float*)d_in[3];
    const float* ln1_g   = (const float*)d_in[4];
    const float* ln1_b   = (const float*)d_in[5];
    const float* ln2_g   = (const float*)d_in[6];
    const float* ln2_b   = (const float*)d_in[7];
    const float* qw      = (const float*)d_in[8];
    const float* qb      = (const float*)d_in[9];
    const float* kw      = (const float*)d_in[10];
    const float* kb      = (const float*)d_in[11];
    const float* vw      = (const float*)d_in[12];
    const float* vb      = (const float*)d_in[13];
    const float* map_w   = (const float*)d_in[14];
    const float* map_b   = (const float*)d_in[15];
    const float* w1      = (const float*)d_in[16];
    const float* b1      = (const float*)d_in[17];
    const float* w2      = (const float*)d_in[18];
    const float* b2      = (const float*)d_in[19];
    const float* cls_w   = (const float*)d_in[20];
    const float* cls_b   = (const float*)d_in[21];

    char* wp = (char*)d_ws;
    auto alloc = [&](size_t bytes) { char* p = wp; wp += (bytes + 255) & ~(size_t)255; return p; };
    const long BT = (long)B_ * T_;                       // 25216

    // ~207 MB total. +64-row pads absorb guard-free tile overreads (finite poison).
    float* xf  = (float*)alloc(BT * D_ * 4);             // x (y in-place after LN2)
    bf16*  hb  = (bf16*) alloc(BT * D_ * 2);             // LN1/LN2 bf16 output
    bf16*  Qh  = (bf16*) alloc((BT + 64) * D_ * 2);      // Q, then V
    bf16*  Kh  = (bf16*) alloc((BT + 64) * D_ * 2);      // K, then av
    float* Sb  = (float*)alloc((long)B_ * T_ * TP_ * 4);
    bf16*  Pb  = (bf16*) alloc((BT + 64) * TP_ * 2);
    bf16*  m1c = (bf16*) alloc((long)CHUNK_ * M_ * 2);   // MLP hidden, chunked
    bf16*  patches = m1c;                                // alias: only used pre-layer0
    bf16*  wq  = (bf16*)alloc((long)NH_ * D_ * D_ * 2);  // per-layer weight staging
    bf16*  wk  = (bf16*)alloc((long)NH_ * D_ * D_ * 2);
    bf16*  wv  = (bf16*)alloc((long)NH_ * D_ * D_ * 2);
    bf16*  wmapP=(bf16*)alloc(((long)NH_ * T_ + 64) * TP_ * 2);
    bf16*  w1l = (bf16*)alloc((long)M_ * D_ * 2);
    bf16*  w2l = (bf16*)alloc((long)D_ * M_ * 2);
    bf16*  wlin= (bf16*)alloc((long)D_ * 256 * 2);

    auto conv = [&](const float* src, bf16* dst, long n) {
        k_f32_to_bf16v<<<1024, 256, 0, stream>>>(src, dst, n / 8);
    };

    conv(lin_w, wlin, (long)D_ * 256);
    {
        long tot = (long)B_ * 196 * 256;
        k_patchify<<<(int)((tot + 255) / 256), 256, 0, stream>>>(images, patches);
        k_cls_token<<<(B_ * D_ + 255) / 256, 256, 0, stream>>>(cls_tok, xf);
        // emb -> x[:,1:,:]
        k_gemm_bt<0><<<dim3(4, 2, B_), 256, 0, stream>>>(
            patches, 256, (long)196 * 256,
            wlin, 256, 0,
            xf + D_, D_, (long)T_ * D_,
            lin_b, nullptr, 0,
            196, D_, 256);
    }

    const float scale = 1.0f / 14.0f;
    const int lnGrid = (int)((BT + 3) / 4);

    for (int l = 0; l < L_; l++) {
        // stage this layer's weights in bf16
        conv(qw + (long)l * NH_ * D_ * D_, wq, (long)NH_ * D_ * D_);
        conv(kw + (long)l * NH_ * D_ * D_, wk, (long)NH_ * D_ * D_);
        conv(vw + (long)l * NH_ * D_ * D_, wv, (long)NH_ * D_ * D_);
        conv(w1 + (long)l * M_ * D_, w1l, (long)M_ * D_);
        conv(w2 + (long)l * D_ * M_, w2l, (long)D_ * M_);
        {
            int tot = NH_ * T_ * TP_;
            k_prep_map<<<(tot + 255) / 256, 256, 0, stream>>>(
                map_w + (long)l * T_ * T_ * NH_, wmapP);
        }

        k_ln<0><<<lnGrid, 256, 0, stream>>>(xf, ln1_g + l * D_, ln1_b + l * D_, hb, nullptr, (int)BT);

        for (int h = 0; h < NH_; h++) {
            int lh = l * NH_ + h;
            // Q -> Qh ; K -> Kh
            k_gemm_bt<1><<<dim3(4, 197, 1), 256, 0, stream>>>(
                hb, D_, 0, wq + (long)h * D_ * D_, D_, 0, Qh, D_, 0,
                qb + (long)lh * D_, nullptr, 0, (int)BT, D_, D_);
            k_gemm_bt<1><<<dim3(4, 197, 1), 256, 0, stream>>>(
                hb, D_, 0, wk + (long)h * D_ * D_, D_, 0, Kh, D_, 0,
                kb + (long)lh * D_, nullptr, 0, (int)BT, D_, D_);

            // S = Q @ K^T  (per image)
            k_gemm_bt<0><<<dim3(2, 2, B_), 256, 0, stream>>>(
                Qh, D_, (long)T_ * D_, Kh, D_, (long)T_ * D_,
                Sb, TP_, (long)T_ * TP_, nullptr, nullptr, 0, T_, T_, D_);

            k_softmax<<<lnGrid, 256, 0, stream>>>(Sb, Pb, (int)(B_ * T_), scale);

            // V -> Qh  (Q is dead after S)
            k_gemm_bt<1><<<dim3(4, 197, 1), 256, 0, stream>>>(
                hb, D_, 0, wv + (long)h * D_ * D_, D_, 0, Qh, D_, 0,
                vb + (long)lh * D_, nullptr, 0, (int)BT, D_, D_);

            // av = P @ V -> Kh  (K is dead after softmax); K padded to 224, P zero-padded
            k_gemm_nn<0><<<dim3(4, 2, B_), 256, 0, stream>>>(
                Pb, TP_, (long)T_ * TP_, Qh, D_, (long)T_ * D_,
                Kh, D_, (long)T_ * D_, nullptr, T_, D_, TP_);

            // x += map_slice @ av   (+ map_b on first head); wmapP zero-K-padded
            k_gemm_nn<1><<<dim3(4, 2, B_), 256, 0, stream>>>(
                wmapP + (long)h * T_ * TP_, TP_, 0,
                Kh, D_, (long)T_ * D_,
                xf, D_, (long)T_ * D_,
                (h == 0) ? (map_b + (long)l * T_) : nullptr,
                T_, D_, TP_);
        }

        // y = LN2(x): bf16 -> hb, f32 in-place over xf (x is dead)
        k_ln<1><<<lnGrid, 256, 0, stream>>>(xf, ln2_g + l * D_, ln2_b + l * D_, hb, xf, (int)BT);

        // MLP in row-chunks: x = y + gelu(y@W1^T+b1)@W2^T+b2
        for (int c = 0; c < 4; c++) {
            long r0 = (long)c * CHUNK_;
            int rows = (c == 3) ? (int)(BT - 3 * CHUNK_) : CHUNK_;   // 6016 or 6400
            k_gemm_bt<2><<<dim3(16, rows / 128, 1), 256, 0, stream>>>(
                hb + r0 * D_, D_, 0, w1l, D_, 0,
                m1c, M_, 0, b1 + (long)l * M_, nullptr, 0, rows, M_, D_);
            k_gemm_bt<3><<<dim3(4, rows / 128, 1), 256, 0, stream>>>(
                m1c, M_, 0, w2l, M_, 0,
                xf + r0 * D_, D_, 0, b2 + (long)l * D_, xf + r0 * D_, D_, rows, D_, M_);
        }
    }

    k_classifier<<<B_, 64, 0, stream>>>(xf, cls_w, cls_b, (float*)d_out);
}

// Round 4
// 14239.543 us; speedup vs baseline: 2.0999x; 1.2138x over previous
//
#include <hip/hip_runtime.h>
#include <hip/hip_bf16.h>
#include <math.h>

#define B_   128
#define HW_  224
#define P_   16
#define D_   512
#define NH_  8
#define L_   6
#define M_   2048
#define NC_  10
#define GP_  14
#define T_   197
#define TP_  224    // padded T (multiple of 32): lda of S/P, K-dim of PV/map gemms
#define EPS_ 1e-5f
#define QKVW_ 1536  // fused per-head QKV output width
#define CH0_ 12672  // MLP chunk 0 rows (99 blocks)
#define CH1_ 12544  // MLP chunk 1 rows (98 blocks)

typedef __hip_bfloat16 bf16;
typedef __attribute__((ext_vector_type(8))) __bf16 bf16x8;
typedef __attribute__((ext_vector_type(4))) float  f32x4;

// async global->LDS, 16B per lane. LDS dest = wave-uniform base + lane*16.
__device__ __forceinline__ void gload16(const void* g, void* l) {
    __builtin_amdgcn_global_load_lds(
        (const __attribute__((address_space(1))) void*)g,
        (__attribute__((address_space(3))) void*)l, 16, 0, 0);
}

// ---------------- elementwise / prep helpers ----------------

__global__ void k_f32_to_bf16v(const float* __restrict__ in, bf16* __restrict__ out, long n8) {
    long stride = (long)gridDim.x * blockDim.x;
    for (long i = (long)blockIdx.x * blockDim.x + threadIdx.x; i < n8; i += stride) {
        float4 a = ((const float4*)in)[i * 2], b = ((const float4*)in)[i * 2 + 1];
        union { uint4 u; bf16 h[8]; } r;
        r.h[0] = __float2bfloat16(a.x); r.h[1] = __float2bfloat16(a.y);
        r.h[2] = __float2bfloat16(a.z); r.h[3] = __float2bfloat16(a.w);
        r.h[4] = __float2bfloat16(b.x); r.h[5] = __float2bfloat16(b.y);
        r.h[6] = __float2bfloat16(b.z); r.h[7] = __float2bfloat16(b.w);
        ((uint4*)out)[i] = r.u;
    }
}

// gather per-layer Q/K/V weights into wqkv[h][1536][512] bf16 (r<512:Q, <1024:K, else V)
__global__ void k_prep_qkvw(const float* __restrict__ qw, const float* __restrict__ kw,
                            const float* __restrict__ vw, bf16* __restrict__ out) {
    int idx = blockIdx.x * blockDim.x + threadIdx.x;        // [h][r][e8]
    if (idx >= NH_ * QKVW_ * (D_ / 8)) return;
    int e8 = idx & 63;
    int t  = idx >> 6;
    int r  = t % QKVW_;
    int h  = t / QKVW_;
    const float* src = (r < 512) ? qw : (r < 1024) ? kw : vw;
    long so = ((long)(h * D_ + (r & 511)) * D_) + e8 * 8;
    float4 a = *(const float4*)(src + so), b = *(const float4*)(src + so + 4);
    union { uint4 u; bf16 hh[8]; } rr;
    rr.hh[0] = __float2bfloat16(a.x); rr.hh[1] = __float2bfloat16(a.y);
    rr.hh[2] = __float2bfloat16(a.z); rr.hh[3] = __float2bfloat16(a.w);
    rr.hh[4] = __float2bfloat16(b.x); rr.hh[5] = __float2bfloat16(b.y);
    rr.hh[6] = __float2bfloat16(b.z); rr.hh[7] = __float2bfloat16(b.w);
    ((uint4*)out)[idx] = rr.u;
}

__global__ void k_prep_qkvb(const float* __restrict__ qb, const float* __restrict__ kb,
                            const float* __restrict__ vb, float* __restrict__ out) {
    int idx = blockIdx.x * blockDim.x + threadIdx.x;
    if (idx >= NH_ * QKVW_) return;
    int r = idx % QKVW_, h = idx / QKVW_;
    const float* src = (r < 512) ? qb : (r < 1024) ? kb : vb;
    out[idx] = src[h * D_ + (r & 511)];
}

__global__ void k_patchify(const float* __restrict__ img, bf16* __restrict__ patches) {
    long idx = (long)blockIdx.x * blockDim.x + threadIdx.x;
    long total = (long)B_ * 196 * 256;
    if (idx >= total) return;
    int q = (int)(idx & 255);
    int p = (int)((idx >> 8) % 196);
    int b = (int)(idx / (196 * 256));
    int gy = p / GP_, gx = p % GP_;
    int py = q >> 4,  px = q & 15;
    patches[idx] = __float2bfloat16(img[((long)b * HW_ + gy * P_ + py) * HW_ + gx * P_ + px]);
}

__global__ void k_cls_token(const float* __restrict__ tok, float* __restrict__ x) {
    int i = blockIdx.x * blockDim.x + threadIdx.x;
    if (i < B_ * D_) {
        int b = i >> 9, d = i & 511;
        x[(long)b * T_ * D_ + d] = tok[d];
    }
}

// map_w[l] is [T][T*NH]; produce per-head zero-K-padded A: out[h][t][s] (lda=TP_)
__global__ void k_prep_map(const float* __restrict__ in, bf16* __restrict__ out) {
    int idx = blockIdx.x * blockDim.x + threadIdx.x;
    int total = NH_ * T_ * TP_;
    if (idx >= total) return;
    int s = idx % TP_;
    int t = (idx / TP_) % T_;
    int h = idx / (TP_ * T_);
    float v = (s < T_) ? in[t * (T_ * NH_) + h * T_ + s] : 0.f;
    out[idx] = __float2bfloat16(v);
}

// ---------------- LayerNorm (one wave per row of 512) ----------------

template<int WRITE_Y>
__global__ __launch_bounds__(256) void k_ln(const float* x,
        const float* __restrict__ g, const float* __restrict__ bb,
        bf16* __restrict__ obf, float* of, int rows) {
    int wid = blockIdx.x * 4 + (threadIdx.x >> 6);
    if (wid >= rows) return;
    int lane = threadIdx.x & 63;
    const float* xr = x + (long)wid * D_;
    float v[8];
    float s = 0.f;
#pragma unroll
    for (int i = 0; i < 8; i++) { v[i] = xr[i * 64 + lane]; s += v[i]; }
#pragma unroll
    for (int off = 32; off; off >>= 1) s += __shfl_xor(s, off, 64);
    float mean = s * (1.f / D_);
    float sq = 0.f;
#pragma unroll
    for (int i = 0; i < 8; i++) { float d = v[i] - mean; sq += d * d; }
#pragma unroll
    for (int off = 32; off; off >>= 1) sq += __shfl_xor(sq, off, 64);
    float inv = rsqrtf(sq * (1.f / D_) + EPS_);
#pragma unroll
    for (int i = 0; i < 8; i++) {
        int d = i * 64 + lane;
        float val = (v[i] - mean) * inv * g[d] + bb[d];
        obf[(long)wid * D_ + d] = __float2bfloat16(val);
        if (WRITE_Y) of[(long)wid * D_ + d] = val;
    }
}

// ---------------- row softmax: S (f32, lda=TP_) -> P (bf16, lda=TP_, zero-padded) ----

__global__ __launch_bounds__(256) void k_softmax(const float* __restrict__ S,
        bf16* __restrict__ Pm, int rows, float scale) {
    int wid = blockIdx.x * 4 + (threadIdx.x >> 6);
    if (wid >= rows) return;
    int lane = threadIdx.x & 63;
    const float* sr = S + (long)wid * TP_;
    bf16* pr = Pm + (long)wid * TP_;
    float v[4];
    float mx = -1e30f;
#pragma unroll
    for (int i = 0; i < 4; i++) {
        int c = i * 64 + lane;
        v[i] = (c < T_) ? sr[c] * scale : -1e30f;
        mx = fmaxf(mx, v[i]);
    }
#pragma unroll
    for (int off = 32; off; off >>= 1) mx = fmaxf(mx, __shfl_xor(mx, off, 64));
    float sum = 0.f;
#pragma unroll
    for (int i = 0; i < 4; i++) {
        int c = i * 64 + lane;
        float e = (c < T_) ? expf(v[i] - mx) : 0.f;
        v[i] = e; sum += e;
    }
#pragma unroll
    for (int off = 32; off; off >>= 1) sum += __shfl_xor(sum, off, 64);
    float inv = 1.f / sum;
#pragma unroll
    for (int i = 0; i < 4; i++) {
        int c = i * 64 + lane;
        if (c < TP_) pr[c] = __float2bfloat16((c < T_) ? v[i] * inv : 0.f);
    }
}

// ---------------- GEMM kernels ----------------

__device__ __forceinline__ float geluf(float v) {
    return 0.5f * v * (1.f + erff(v * 0.70710678118654752f));
}

// C[M,N] = A[M,K] @ B[N,K]^T.  Guard-free loads (caller guarantees overreads are
// in-bounds-of-workspace and finite); stores guarded by Mt/Nt. K % 32 == 0.
// MODE 0: f32 store (v + bias?)       MODE 1: bf16 store (v + bias)
// MODE 2: bf16 store gelu(v + bias)   MODE 3: f32 store (v + bias + res)  (res may alias C)
template<int MODE>
__global__ __launch_bounds__(256) void k_gemm_bt(
        const bf16* __restrict__ A, long lda, long bsA,
        const bf16* __restrict__ Bw, long ldb, long bsB,
        void* __restrict__ Cp, long ldc, long bsC,
        const float* __restrict__ bias,
        const float* res, long ldres,
        int Mt, int Nt, int Kt) {
    __shared__ __align__(16) bf16 As[128][32];
    __shared__ __align__(16) bf16 Bs[128][32];
    int bz = blockIdx.z;
    A  += (long)bz * bsA;
    Bw += (long)bz * bsB;
    int m0 = blockIdx.y * 128, n0 = blockIdx.x * 128;
    int tid = threadIdx.x;
    int wv = tid >> 6, lane = tid & 63;
    int wm = (wv >> 1) * 64, wn = (wv & 1) * 64;
    int lrow = lane & 15, koff = (lane >> 4) * 8;

    int rA = tid >> 2, pA = (tid & 3) * 8;          // 64 rows per 256-thread pass
    const bf16* gA0 = A  + (long)(m0 + rA) * lda + pA;
    const bf16* gA1 = A  + (long)(m0 + 64 + rA) * lda + pA;
    const bf16* gB0 = Bw + (long)(n0 + rA) * ldb + pA;
    const bf16* gB1 = Bw + (long)(n0 + 64 + rA) * ldb + pA;
    char* lA0 = (char*)As + (wv * 64) * 16;         // wave-uniform LDS bases
    char* lA1 = (char*)As + (256 + wv * 64) * 16;
    char* lB0 = (char*)Bs + (wv * 64) * 16;
    char* lB1 = (char*)Bs + (256 + wv * 64) * 16;

    f32x4 acc[4][4];
#pragma unroll
    for (int i = 0; i < 4; i++)
#pragma unroll
        for (int j = 0; j < 4; j++) acc[i][j] = (f32x4){0.f, 0.f, 0.f, 0.f};

    int kTiles = Kt >> 5;
    for (int kt = 0; kt < kTiles; kt++) {
        long k0 = (long)kt << 5;
        gload16(gA0 + k0, lA0);
        gload16(gA1 + k0, lA1);
        gload16(gB0 + k0, lB0);
        gload16(gB1 + k0, lB1);
        __syncthreads();
        bf16x8 af[4], bfr[4];
#pragma unroll
        for (int mi = 0; mi < 4; mi++) af[mi]  = *(const bf16x8*)&As[wm + mi * 16 + lrow][koff];
#pragma unroll
        for (int ni = 0; ni < 4; ni++) bfr[ni] = *(const bf16x8*)&Bs[wn + ni * 16 + lrow][koff];
#pragma unroll
        for (int mi = 0; mi < 4; mi++)
#pragma unroll
            for (int ni = 0; ni < 4; ni++)
                acc[mi][ni] = __builtin_amdgcn_mfma_f32_16x16x32_bf16(af[mi], bfr[ni], acc[mi][ni], 0, 0, 0);
        __syncthreads();
    }

    int r4 = (lane >> 4) * 4, c1 = lane & 15;
#pragma unroll
    for (int mi = 0; mi < 4; mi++) {
#pragma unroll
        for (int r = 0; r < 4; r++) {
            int row = m0 + wm + mi * 16 + r4 + r;
            if (row >= Mt) continue;
#pragma unroll
            for (int ni = 0; ni < 4; ni++) {
                int col = n0 + wn + ni * 16 + c1;
                if (col >= Nt) continue;
                float v = acc[mi][ni][r];
                if (bias) v += bias[col];
                long cidx = (long)bz * bsC + (long)row * ldc + col;
                if (MODE == 0)      ((float*)Cp)[cidx] = v;
                else if (MODE == 1) ((bf16*)Cp)[cidx]  = __float2bfloat16(v);
                else if (MODE == 2) ((bf16*)Cp)[cidx]  = __float2bfloat16(geluf(v));
                else                ((float*)Cp)[cidx] = v + res[(long)row * ldres + col];
            }
        }
    }
}

// C[M,N] (op)= A[M,K] @ B[K,N], B row-major KxN. Guard-free loads; K % 32 == 0
// (caller zero-pads the ragged K on the A side). Stores guarded.
// MODE 0: bf16 store.   MODE 1: f32 accumulate C += v + rowbias[row] (rowbias optional)
template<int MODE>
__global__ __launch_bounds__(256) void k_gemm_nn(
        const bf16* __restrict__ A, long lda, long bsA,
        const bf16* __restrict__ Bw, long ldb, long bsB,
        void* __restrict__ Cp, long ldc, long bsC,
        const float* __restrict__ rowbias,
        int Mt, int Nt, int Kt) {
    __shared__ __align__(16) bf16 As[128][32];
    __shared__ __align__(16) bf16 Bs[128][32];
    int bz = blockIdx.z;
    A  += (long)bz * bsA;
    Bw += (long)bz * bsB;
    int m0 = blockIdx.y * 128, n0 = blockIdx.x * 128;
    int tid = threadIdx.x;
    int wv = tid >> 6, lane = tid & 63;
    int wm = (wv >> 1) * 64, wn = (wv & 1) * 64;
    int lrow = lane & 15, koff = (lane >> 4) * 8;

    int rA = tid >> 2, pA = (tid & 3) * 8;
    const bf16* gA0 = A + (long)(m0 + rA) * lda + pA;
    const bf16* gA1 = A + (long)(m0 + 64 + rA) * lda + pA;
    char* lA0 = (char*)As + (wv * 64) * 16;
    char* lA1 = (char*)As + (256 + wv * 64) * 16;
    int bk = tid & 31, bg = tid >> 5;               // B transpose staging coords

    f32x4 acc[4][4];
#pragma unroll
    for (int i = 0; i < 4; i++)
#pragma unroll
        for (int j = 0; j < 4; j++) acc[i][j] = (f32x4){0.f, 0.f, 0.f, 0.f};

    int kTiles = Kt >> 5;
    for (int kt = 0; kt < kTiles; kt++) {
        long k0 = (long)kt << 5;
        gload16(gA0 + k0, lA0);
        gload16(gA1 + k0, lA1);
#pragma unroll
        for (int i = 0; i < 2; i++) {
            int g = bg + 8 * i;
            uint4 v = *(const uint4*)(Bw + (k0 + bk) * ldb + n0 + g * 8);
            const bf16* pv = (const bf16*)&v;
#pragma unroll
            for (int j = 0; j < 8; j++) Bs[g * 8 + j][bk] = pv[j];
        }
        __syncthreads();
        bf16x8 af[4], bfr[4];
#pragma unroll
        for (int mi = 0; mi < 4; mi++) af[mi]  = *(const bf16x8*)&As[wm + mi * 16 + lrow][koff];
#pragma unroll
        for (int ni = 0; ni < 4; ni++) bfr[ni] = *(const bf16x8*)&Bs[wn + ni * 16 + lrow][koff];
#pragma unroll
        for (int mi = 0; mi < 4; mi++)
#pragma unroll
            for (int ni = 0; ni < 4; ni++)
                acc[mi][ni] = __builtin_amdgcn_mfma_f32_16x16x32_bf16(af[mi], bfr[ni], acc[mi][ni], 0, 0, 0);
        __syncthreads();
    }

    int r4 = (lane >> 4) * 4, c1 = lane & 15;
#pragma unroll
    for (int mi = 0; mi < 4; mi++) {
#pragma unroll
        for (int r = 0; r < 4; r++) {
            int row = m0 + wm + mi * 16 + r4 + r;
            if (row >= Mt) continue;
#pragma unroll
            for (int ni = 0; ni < 4; ni++) {
                int col = n0 + wn + ni * 16 + c1;
                if (col >= Nt) continue;
                float v = acc[mi][ni][r];
                long cidx = (long)bz * bsC + (long)row * ldc + col;
                if (MODE == 0) {
                    ((bf16*)Cp)[cidx] = __float2bfloat16(v);
                } else {
                    if (rowbias) v += rowbias[row];
                    ((float*)Cp)[cidx] += v;
                }
            }
        }
    }
}

// ---------------- classifier + softmax ----------------

__global__ __launch_bounds__(64) void k_classifier(const float* __restrict__ x,
        const float* __restrict__ w, const float* __restrict__ bias, float* __restrict__ out) {
    int b = blockIdx.x, lane = threadIdx.x;
    const float* xr = x + (long)b * T_ * D_;   // row 0 = cls token
    float logits[NC_];
#pragma unroll
    for (int c = 0; c < NC_; c++) {
        float s = 0.f;
        for (int d = lane; d < D_; d += 64) s += xr[d] * w[c * D_ + d];
#pragma unroll
        for (int off = 32; off; off >>= 1) s += __shfl_xor(s, off, 64);
        logits[c] = s + bias[c];
    }
    float mx = -1e30f;
#pragma unroll
    for (int c = 0; c < NC_; c++) mx = fmaxf(mx, logits[c]);
    float sum = 0.f;
#pragma unroll
    for (int c = 0; c < NC_; c++) { float e = expf(logits[c] - mx); logits[c] = e; sum += e; }
    if (lane == 0) {
        float inv = 1.f / sum;
#pragma unroll
        for (int c = 0; c < NC_; c++) out[(long)b * NC_ + c] = logits[c] * inv;
    }
}

// ---------------- host ----------------

extern "C" void kernel_launch(void* const* d_in, const int* in_sizes, int n_in,
                              void* d_out, int out_size, void* d_ws, size_t ws_size,
                              hipStream_t stream) {
    const float* images  = (const float*)d_in[0];
    const float* lin_w   = (const float*)d_in[1];
    const float* lin_b   = (const float*)d_in[2];
    const float* cls_tok = (const float*)d_in[3];
    const float* ln1_g   = (const float*)d_in[4];
    const float* ln1_b   = (const float*)d_in[5];
    const float* ln2_g   = (const float*)d_in[6];
    const float* ln2_b   = (const float*)d_in[7];
    const float* qw      = (const float*)d_in[8];
    const float* qb      = (const float*)d_in[9];
    const float* kw      = (const float*)d_in[10];
    const float* kb      = (const float*)d_in[11];
    const float* vw      = (const float*)d_in[12];
    const float* vb      = (const float*)d_in[13];
    const float* map_w   = (const float*)d_in[14];
    const float* map_b   = (const float*)d_in[15];
    const float* w1      = (const float*)d_in[16];
    const float* b1      = (const float*)d_in[17];
    const float* w2      = (const float*)d_in[18];
    const float* b2      = (const float*)d_in[19];
    const float* cls_w   = (const float*)d_in[20];
    const float* cls_b   = (const float*)d_in[21];

    char* wp = (char*)d_ws;
    auto alloc = [&](size_t bytes) { char* p = wp; wp += (bytes + 255) & ~(size_t)255; return p; };
    const long BT = (long)B_ * T_;                       // 25216

    // ~236 MB total. +64-row pads absorb guard-free tile overreads (finite poison).
    float* xf   = (float*)alloc(BT * D_ * 4);            // x (y in-place after LN2)
    bf16*  hb   = (bf16*) alloc(BT * D_ * 2);            // LN1/LN2 bf16 output
    bf16*  QKVh = (bf16*) alloc((BT + 64) * QKVW_ * 2);  // per-head fused Q|K|V; av over Q
    bf16*  Pb   = (bf16*) alloc((BT + 64) * TP_ * 2);
    char*  scratch = alloc((long)CH0_ * M_ * 2);         // m1c (MLP) ∪ Sb (attn) ∪ patches
    float* Sb   = (float*)scratch;
    bf16*  m1c  = (bf16*) scratch;
    bf16*  patches = (bf16*)scratch;
    bf16*  wqkv = (bf16*)alloc((long)NH_ * QKVW_ * D_ * 2);
    float* qkvb = (float*)alloc((long)NH_ * QKVW_ * 4);
    bf16*  wmapP= (bf16*)alloc(((long)NH_ * T_ + 64) * TP_ * 2);
    bf16*  w1l  = (bf16*)alloc((long)M_ * D_ * 2);
    bf16*  w2l  = (bf16*)alloc((long)D_ * M_ * 2);
    bf16*  wlin = (bf16*)alloc((long)D_ * 256 * 2);

    auto conv = [&](const float* src, bf16* dst, long n) {
        k_f32_to_bf16v<<<1024, 256, 0, stream>>>(src, dst, n / 8);
    };

    conv(lin_w, wlin, (long)D_ * 256);
    {
        long tot = (long)B_ * 196 * 256;
        k_patchify<<<(int)((tot + 255) / 256), 256, 0, stream>>>(images, patches);
        k_cls_token<<<(B_ * D_ + 255) / 256, 256, 0, stream>>>(cls_tok, xf);
        // emb -> x[:,1:,:]
        k_gemm_bt<0><<<dim3(4, 2, B_), 256, 0, stream>>>(
            patches, 256, (long)196 * 256,
            wlin, 256, 0,
            xf + D_, D_, (long)T_ * D_,
            lin_b, nullptr, 0,
            196, D_, 256);
    }

    const float scale = 1.0f / 14.0f;
    const int lnGrid = (int)((BT + 3) / 4);

    for (int l = 0; l < L_; l++) {
        // stage this layer's weights
        k_prep_qkvw<<<(NH_ * QKVW_ * (D_ / 8) + 255) / 256, 256, 0, stream>>>(
            qw + (long)l * NH_ * D_ * D_, kw + (long)l * NH_ * D_ * D_,
            vw + (long)l * NH_ * D_ * D_, wqkv);
        k_prep_qkvb<<<(NH_ * QKVW_ + 255) / 256, 256, 0, stream>>>(
            qb + (long)l * NH_ * D_, kb + (long)l * NH_ * D_,
            vb + (long)l * NH_ * D_, qkvb);
        conv(w1 + (long)l * M_ * D_, w1l, (long)M_ * D_);
        conv(w2 + (long)l * D_ * M_, w2l, (long)D_ * M_);
        {
            int tot = NH_ * T_ * TP_;
            k_prep_map<<<(tot + 255) / 256, 256, 0, stream>>>(
                map_w + (long)l * T_ * T_ * NH_, wmapP);
        }

        k_ln<0><<<lnGrid, 256, 0, stream>>>(xf, ln1_g + l * D_, ln1_b + l * D_, hb, nullptr, (int)BT);

        for (int h = 0; h < NH_; h++) {
            // fused [Q|K|V] -> QKVh columns [0|512|1024]
            k_gemm_bt<1><<<dim3(12, 197, 1), 256, 0, stream>>>(
                hb, D_, 0, wqkv + (long)h * QKVW_ * D_, D_, 0,
                QKVh, QKVW_, 0, qkvb + (long)h * QKVW_, nullptr, 0,
                (int)BT, QKVW_, D_);

            // S = Q @ K^T  (per image)
            k_gemm_bt<0><<<dim3(2, 2, B_), 256, 0, stream>>>(
                QKVh, QKVW_, (long)T_ * QKVW_, QKVh + 512, QKVW_, (long)T_ * QKVW_,
                Sb, TP_, (long)T_ * TP_, nullptr, nullptr, 0, T_, T_, D_);

            k_softmax<<<lnGrid, 256, 0, stream>>>(Sb, Pb, (int)BT, scale);

            // av = P @ V  -> overwrite Q columns (dead after S)
            k_gemm_nn<0><<<dim3(4, 2, B_), 256, 0, stream>>>(
                Pb, TP_, (long)T_ * TP_, QKVh + 1024, QKVW_, (long)T_ * QKVW_,
                QKVh, QKVW_, (long)T_ * QKVW_, nullptr, T_, D_, TP_);

            // x += map_slice @ av   (+ map_b on first head)
            k_gemm_nn<1><<<dim3(4, 2, B_), 256, 0, stream>>>(
                wmapP + (long)h * T_ * TP_, TP_, 0,
                QKVh, QKVW_, (long)T_ * QKVW_,
                xf, D_, (long)T_ * D_,
                (h == 0) ? (map_b + (long)l * T_) : nullptr,
                T_, D_, TP_);
        }

        // y = LN2(x): bf16 -> hb, f32 in-place over xf (x is dead)
        k_ln<1><<<lnGrid, 256, 0, stream>>>(xf, ln2_g + l * D_, ln2_b + l * D_, hb, xf, (int)BT);

        // MLP in 2 row-chunks (12672 + 12544, both exact 128-multiples)
        long r0 = 0;
        for (int c = 0; c < 2; c++) {
            int rows = (c == 0) ? CH0_ : CH1_;
            k_gemm_bt<2><<<dim3(16, rows / 128, 1), 256, 0, stream>>>(
                hb + r0 * D_, D_, 0, w1l, D_, 0,
                m1c, M_, 0, b1 + (long)l * M_, nullptr, 0, rows, M_, D_);
            k_gemm_bt<3><<<dim3(4, rows / 128, 1), 256, 0, stream>>>(
                m1c, M_, 0, w2l, M_, 0,
                xf + r0 * D_, D_, 0, b2 + (long)l * D_, xf + r0 * D_, D_, rows, D_, M_);
            r0 += rows;
        }
    }

    k_classifier<<<B_, 64, 0, stream>>>(xf, cls_w, cls_b, (float*)d_out);
}

// Round 5
// 13492.459 us; speedup vs baseline: 2.2162x; 1.0554x over previous
//
#include <hip/hip_runtime.h>
#include <hip/hip_bf16.h>
#include <math.h>

#define B_   128
#define HW_  224
#define P_   16
#define D_   512
#define NH_  8
#define L_   6
#define M_   2048
#define NC_  10
#define GP_  14
#define T_   197
#define TP_  224    // padded T (multiple of 32): lda of P/R, K-dim of R/RV gemms
#define EPS_ 1e-5f
#define QKVW_ 1536  // fused per-head QKV output width
#define CH0_ 12672  // MLP chunk 0 rows (99 blocks)
#define CH1_ 12544  // MLP chunk 1 rows (98 blocks)

typedef __hip_bfloat16 bf16;
typedef __attribute__((ext_vector_type(8))) __bf16 bf16x8;
typedef __attribute__((ext_vector_type(4))) float  f32x4;

// async global->LDS, 16B per lane. LDS dest = wave-uniform base + lane*16.
__device__ __forceinline__ void gload16(const void* g, void* l) {
    __builtin_amdgcn_global_load_lds(
        (const __attribute__((address_space(1))) void*)g,
        (__attribute__((address_space(3))) void*)l, 16, 0, 0);
}

// ---------------- elementwise / prep helpers ----------------

__global__ void k_f32_to_bf16v(const float* __restrict__ in, bf16* __restrict__ out, long n8) {
    long stride = (long)gridDim.x * blockDim.x;
    for (long i = (long)blockIdx.x * blockDim.x + threadIdx.x; i < n8; i += stride) {
        float4 a = ((const float4*)in)[i * 2], b = ((const float4*)in)[i * 2 + 1];
        union { uint4 u; bf16 h[8]; } r;
        r.h[0] = __float2bfloat16(a.x); r.h[1] = __float2bfloat16(a.y);
        r.h[2] = __float2bfloat16(a.z); r.h[3] = __float2bfloat16(a.w);
        r.h[4] = __float2bfloat16(b.x); r.h[5] = __float2bfloat16(b.y);
        r.h[6] = __float2bfloat16(b.z); r.h[7] = __float2bfloat16(b.w);
        ((uint4*)out)[i] = r.u;
    }
}

// gather per-layer Q/K/V weights into wqkv[h][1536][512] bf16 (r<512:Q, <1024:K, else V)
__global__ void k_prep_qkvw(const float* __restrict__ qw, const float* __restrict__ kw,
                            const float* __restrict__ vw, bf16* __restrict__ out) {
    int idx = blockIdx.x * blockDim.x + threadIdx.x;        // [h][r][e8]
    if (idx >= NH_ * QKVW_ * (D_ / 8)) return;
    int e8 = idx & 63;
    int t  = idx >> 6;
    int r  = t % QKVW_;
    int h  = t / QKVW_;
    const float* src = (r < 512) ? qw : (r < 1024) ? kw : vw;
    long so = ((long)(h * D_ + (r & 511)) * D_) + e8 * 8;
    float4 a = *(const float4*)(src + so), b = *(const float4*)(src + so + 4);
    union { uint4 u; bf16 hh[8]; } rr;
    rr.hh[0] = __float2bfloat16(a.x); rr.hh[1] = __float2bfloat16(a.y);
    rr.hh[2] = __float2bfloat16(a.z); rr.hh[3] = __float2bfloat16(a.w);
    rr.hh[4] = __float2bfloat16(b.x); rr.hh[5] = __float2bfloat16(b.y);
    rr.hh[6] = __float2bfloat16(b.z); rr.hh[7] = __float2bfloat16(b.w);
    ((uint4*)out)[idx] = rr.u;
}

__global__ void k_prep_qkvb(const float* __restrict__ qb, const float* __restrict__ kb,
                            const float* __restrict__ vb, float* __restrict__ out) {
    int idx = blockIdx.x * blockDim.x + threadIdx.x;
    if (idx >= NH_ * QKVW_) return;
    int r = idx % QKVW_, h = idx / QKVW_;
    const float* src = (r < 512) ? qb : (r < 1024) ? kb : vb;
    out[idx] = src[h * D_ + (r & 511)];
}

__global__ void k_patchify(const float* __restrict__ img, bf16* __restrict__ patches) {
    long idx = (long)blockIdx.x * blockDim.x + threadIdx.x;
    long total = (long)B_ * 196 * 256;
    if (idx >= total) return;
    int q = (int)(idx & 255);
    int p = (int)((idx >> 8) % 196);
    int b = (int)(idx / (196 * 256));
    int gy = p / GP_, gx = p % GP_;
    int py = q >> 4,  px = q & 15;
    patches[idx] = __float2bfloat16(img[((long)b * HW_ + gy * P_ + py) * HW_ + gx * P_ + px]);
}

__global__ void k_cls_token(const float* __restrict__ tok, float* __restrict__ x) {
    int i = blockIdx.x * blockDim.x + threadIdx.x;
    if (i < B_ * D_) {
        int b = i >> 9, d = i & 511;
        x[(long)b * T_ * D_ + d] = tok[d];
    }
}

// map_w[l] is [T][T*NH]; produce per-head zero-K-padded A: out[h][t][s] (lda=TP_)
__global__ void k_prep_map(const float* __restrict__ in, bf16* __restrict__ out) {
    int idx = blockIdx.x * blockDim.x + threadIdx.x;
    int total = NH_ * T_ * TP_;
    if (idx >= total) return;
    int s = idx % TP_;
    int t = (idx / TP_) % T_;
    int h = idx / (TP_ * T_);
    float v = (s < T_) ? in[t * (T_ * NH_) + h * T_ + s] : 0.f;
    out[idx] = __float2bfloat16(v);
}

// ---------------- LayerNorm (one wave per row of 512) ----------------

template<int WRITE_Y>
__global__ __launch_bounds__(256) void k_ln(const float* x,
        const float* __restrict__ g, const float* __restrict__ bb,
        bf16* __restrict__ obf, float* of, int rows) {
    int wid = blockIdx.x * 4 + (threadIdx.x >> 6);
    if (wid >= rows) return;
    int lane = threadIdx.x & 63;
    const float* xr = x + (long)wid * D_;
    float v[8];
    float s = 0.f;
#pragma unroll
    for (int i = 0; i < 8; i++) { v[i] = xr[i * 64 + lane]; s += v[i]; }
#pragma unroll
    for (int off = 32; off; off >>= 1) s += __shfl_xor(s, off, 64);
    float mean = s * (1.f / D_);
    float sq = 0.f;
#pragma unroll
    for (int i = 0; i < 8; i++) { float d = v[i] - mean; sq += d * d; }
#pragma unroll
    for (int off = 32; off; off >>= 1) sq += __shfl_xor(sq, off, 64);
    float inv = rsqrtf(sq * (1.f / D_) + EPS_);
#pragma unroll
    for (int i = 0; i < 8; i++) {
        int d = i * 64 + lane;
        float val = (v[i] - mean) * inv * g[d] + bb[d];
        obf[(long)wid * D_ + d] = __float2bfloat16(val);
        if (WRITE_Y) of[(long)wid * D_ + d] = val;
    }
}

// ---------------- fused S = QK^T (scaled) + row-softmax -> P (bf16, zero-padded) ----
// Block = (image z, 64 q-rows). 4 waves; wave w computes q-rows [16w,16w+16) x 224 keys.

__global__ __launch_bounds__(256) void k_attn_ssm(
        const bf16* __restrict__ QKV, bf16* __restrict__ Pm, float scale) {
    __shared__ __align__(16) bf16 Qs[64][32];
    __shared__ __align__(16) bf16 Ks[256][32];
    int z = blockIdx.z;
    int q0 = blockIdx.y * 64;
    int tid = threadIdx.x;
    int wv = tid >> 6, lane = tid & 63;
    int rA = tid >> 2, pA = (tid & 3) * 8;

    const bf16* Qb = QKV + ((long)z * T_ + q0 + rA) * QKVW_ + pA;       // Q cols 0..511
    const bf16* Kb = QKV + ((long)z * T_ + rA) * QKVW_ + 512 + pA;      // K cols 512..1023
    char* lQ = (char*)Qs + (wv * 16) * 64;

    f32x4 acc[14];
#pragma unroll
    for (int f = 0; f < 14; f++) acc[f] = (f32x4){0.f, 0.f, 0.f, 0.f};

    for (int kt = 0; kt < 16; kt++) {
        long k0 = (long)kt * 32;
        gload16(Qb + k0, lQ);
#pragma unroll
        for (int p = 0; p < 4; p++)
            gload16(Kb + ((long)p * 64) * QKVW_ + k0, (char*)Ks + (p * 64 + wv * 16) * 64);
        __syncthreads();
        bf16x8 af = *(const bf16x8*)&Qs[wv * 16 + (lane & 15)][(lane >> 4) * 8];
#pragma unroll
        for (int f = 0; f < 14; f++) {
            bf16x8 bfr = *(const bf16x8*)&Ks[f * 16 + (lane & 15)][(lane >> 4) * 8];
            acc[f] = __builtin_amdgcn_mfma_f32_16x16x32_bf16(af, bfr, acc[f], 0, 0, 0);
        }
        __syncthreads();
    }

    int c1 = lane & 15, grp = lane >> 4;
    float mx[4] = {-1e30f, -1e30f, -1e30f, -1e30f};
    float sm[4] = {0.f, 0.f, 0.f, 0.f};
#pragma unroll
    for (int f = 0; f < 14; f++) {
        int col = f * 16 + c1;
        bool val = (col < T_);
#pragma unroll
        for (int r = 0; r < 4; r++) {
            float v = val ? acc[f][r] * scale : -1e30f;
            acc[f][r] = v;
            mx[r] = fmaxf(mx[r], v);
        }
    }
#pragma unroll
    for (int r = 0; r < 4; r++)
#pragma unroll
        for (int off = 1; off < 16; off <<= 1) mx[r] = fmaxf(mx[r], __shfl_xor(mx[r], off, 64));
#pragma unroll
    for (int f = 0; f < 14; f++) {
        int col = f * 16 + c1;
        bool val = (col < T_);
#pragma unroll
        for (int r = 0; r < 4; r++) {
            float e = val ? expf(acc[f][r] - mx[r]) : 0.f;
            acc[f][r] = e;
            sm[r] += e;
        }
    }
#pragma unroll
    for (int r = 0; r < 4; r++) {
#pragma unroll
        for (int off = 1; off < 16; off <<= 1) sm[r] += __shfl_xor(sm[r], off, 64);
        sm[r] = 1.f / sm[r];
    }
#pragma unroll
    for (int f = 0; f < 14; f++)
#pragma unroll
        for (int r = 0; r < 4; r++) {
            int qi = q0 + wv * 16 + grp * 4 + r;
            if (qi < T_)
                Pm[((long)z * T_ + qi) * TP_ + f * 16 + c1] = __float2bfloat16(acc[f][r] * sm[r]);
        }
}

// ---------------- GEMM kernels ----------------

__device__ __forceinline__ float geluf(float v) {
    return 0.5f * v * (1.f + erff(v * 0.70710678118654752f));
}

// C[M,N] = A[M,K] @ B[N,K]^T.  Guard-free loads (caller guarantees overreads are
// in-bounds-of-workspace and finite); stores guarded by Mt/Nt. K % 32 == 0.
// MODE 0: f32 store (v + bias?)       MODE 1: bf16 store (v + bias)
// MODE 2: bf16 store gelu(v + bias)   MODE 3: f32 store (v + bias + res)  (res may alias C)
template<int MODE>
__global__ __launch_bounds__(256) void k_gemm_bt(
        const bf16* __restrict__ A, long lda, long bsA,
        const bf16* __restrict__ Bw, long ldb, long bsB,
        void* __restrict__ Cp, long ldc, long bsC,
        const float* __restrict__ bias,
        const float* res, long ldres,
        int Mt, int Nt, int Kt) {
    __shared__ __align__(16) bf16 As[128][32];
    __shared__ __align__(16) bf16 Bs[128][32];
    int bz = blockIdx.z;
    A  += (long)bz * bsA;
    Bw += (long)bz * bsB;
    int m0 = blockIdx.y * 128, n0 = blockIdx.x * 128;
    int tid = threadIdx.x;
    int wv = tid >> 6, lane = tid & 63;
    int wm = (wv >> 1) * 64, wn = (wv & 1) * 64;
    int lrow = lane & 15, koff = (lane >> 4) * 8;

    int rA = tid >> 2, pA = (tid & 3) * 8;          // 64 rows per 256-thread pass
    const bf16* gA0 = A  + (long)(m0 + rA) * lda + pA;
    const bf16* gA1 = A  + (long)(m0 + 64 + rA) * lda + pA;
    const bf16* gB0 = Bw + (long)(n0 + rA) * ldb + pA;
    const bf16* gB1 = Bw + (long)(n0 + 64 + rA) * ldb + pA;
    char* lA0 = (char*)As + (wv * 64) * 16;         // wave-uniform LDS bases
    char* lA1 = (char*)As + (256 + wv * 64) * 16;
    char* lB0 = (char*)Bs + (wv * 64) * 16;
    char* lB1 = (char*)Bs + (256 + wv * 64) * 16;

    f32x4 acc[4][4];
#pragma unroll
    for (int i = 0; i < 4; i++)
#pragma unroll
        for (int j = 0; j < 4; j++) acc[i][j] = (f32x4){0.f, 0.f, 0.f, 0.f};

    int kTiles = Kt >> 5;
    for (int kt = 0; kt < kTiles; kt++) {
        long k0 = (long)kt << 5;
        gload16(gA0 + k0, lA0);
        gload16(gA1 + k0, lA1);
        gload16(gB0 + k0, lB0);
        gload16(gB1 + k0, lB1);
        __syncthreads();
        bf16x8 af[4], bfr[4];
#pragma unroll
        for (int mi = 0; mi < 4; mi++) af[mi]  = *(const bf16x8*)&As[wm + mi * 16 + lrow][koff];
#pragma unroll
        for (int ni = 0; ni < 4; ni++) bfr[ni] = *(const bf16x8*)&Bs[wn + ni * 16 + lrow][koff];
#pragma unroll
        for (int mi = 0; mi < 4; mi++)
#pragma unroll
            for (int ni = 0; ni < 4; ni++)
                acc[mi][ni] = __builtin_amdgcn_mfma_f32_16x16x32_bf16(af[mi], bfr[ni], acc[mi][ni], 0, 0, 0);
        __syncthreads();
    }

    int r4 = (lane >> 4) * 4, c1 = lane & 15;
#pragma unroll
    for (int mi = 0; mi < 4; mi++) {
#pragma unroll
        for (int r = 0; r < 4; r++) {
            int row = m0 + wm + mi * 16 + r4 + r;
            if (row >= Mt) continue;
#pragma unroll
            for (int ni = 0; ni < 4; ni++) {
                int col = n0 + wn + ni * 16 + c1;
                if (col >= Nt) continue;
                float v = acc[mi][ni][r];
                if (bias) v += bias[col];
                long cidx = (long)bz * bsC + (long)row * ldc + col;
                if (MODE == 0)      ((float*)Cp)[cidx] = v;
                else if (MODE == 1) ((bf16*)Cp)[cidx]  = __float2bfloat16(v);
                else if (MODE == 2) ((bf16*)Cp)[cidx]  = __float2bfloat16(geluf(v));
                else                ((float*)Cp)[cidx] = v + res[(long)row * ldres + col];
            }
        }
    }
}

// C[M,N] (op)= A[M,K] @ B[K,N], B row-major KxN. Guard-free loads; K % 32 == 0
// (caller zero-pads the ragged K on the A side). Stores guarded.
// MODE 0: bf16 store.   MODE 1: f32 accumulate C += v + rowbias[row] (rowbias optional)
template<int MODE>
__global__ __launch_bounds__(256) void k_gemm_nn(
        const bf16* __restrict__ A, long lda, long bsA,
        const bf16* __restrict__ Bw, long ldb, long bsB,
        void* __restrict__ Cp, long ldc, long bsC,
        const float* __restrict__ rowbias,
        int Mt, int Nt, int Kt) {
    __shared__ __align__(16) bf16 As[128][32];
    __shared__ __align__(16) bf16 Bs[128][32];
    int bz = blockIdx.z;
    A  += (long)bz * bsA;
    Bw += (long)bz * bsB;
    int m0 = blockIdx.y * 128, n0 = blockIdx.x * 128;
    int tid = threadIdx.x;
    int wv = tid >> 6, lane = tid & 63;
    int wm = (wv >> 1) * 64, wn = (wv & 1) * 64;
    int lrow = lane & 15, koff = (lane >> 4) * 8;

    int rA = tid >> 2, pA = (tid & 3) * 8;
    const bf16* gA0 = A + (long)(m0 + rA) * lda + pA;
    const bf16* gA1 = A + (long)(m0 + 64 + rA) * lda + pA;
    char* lA0 = (char*)As + (wv * 64) * 16;
    char* lA1 = (char*)As + (256 + wv * 64) * 16;
    int bk = tid & 31, bg = tid >> 5;               // B transpose staging coords

    f32x4 acc[4][4];
#pragma unroll
    for (int i = 0; i < 4; i++)
#pragma unroll
        for (int j = 0; j < 4; j++) acc[i][j] = (f32x4){0.f, 0.f, 0.f, 0.f};

    int kTiles = Kt >> 5;
    for (int kt = 0; kt < kTiles; kt++) {
        long k0 = (long)kt << 5;
        gload16(gA0 + k0, lA0);
        gload16(gA1 + k0, lA1);
#pragma unroll
        for (int i = 0; i < 2; i++) {
            int g = bg + 8 * i;
            uint4 v = *(const uint4*)(Bw + (k0 + bk) * ldb + n0 + g * 8);
            const bf16* pv = (const bf16*)&v;
#pragma unroll
            for (int j = 0; j < 8; j++) Bs[g * 8 + j][bk] = pv[j];
        }
        __syncthreads();
        bf16x8 af[4], bfr[4];
#pragma unroll
        for (int mi = 0; mi < 4; mi++) af[mi]  = *(const bf16x8*)&As[wm + mi * 16 + lrow][koff];
#pragma unroll
        for (int ni = 0; ni < 4; ni++) bfr[ni] = *(const bf16x8*)&Bs[wn + ni * 16 + lrow][koff];
#pragma unroll
        for (int mi = 0; mi < 4; mi++)
#pragma unroll
            for (int ni = 0; ni < 4; ni++)
                acc[mi][ni] = __builtin_amdgcn_mfma_f32_16x16x32_bf16(af[mi], bfr[ni], acc[mi][ni], 0, 0, 0);
        __syncthreads();
    }

    int r4 = (lane >> 4) * 4, c1 = lane & 15;
#pragma unroll
    for (int mi = 0; mi < 4; mi++) {
#pragma unroll
        for (int r = 0; r < 4; r++) {
            int row = m0 + wm + mi * 16 + r4 + r;
            if (row >= Mt) continue;
#pragma unroll
            for (int ni = 0; ni < 4; ni++) {
                int col = n0 + wn + ni * 16 + c1;
                if (col >= Nt) continue;
                float v = acc[mi][ni][r];
                long cidx = (long)bz * bsC + (long)row * ldc + col;
                if (MODE == 0) {
                    ((bf16*)Cp)[cidx] = __float2bfloat16(v);
                } else {
                    if (rowbias) v += rowbias[row];
                    ((float*)Cp)[cidx] += v;
                }
            }
        }
    }
}

// ---------------- classifier + softmax ----------------

__global__ __launch_bounds__(64) void k_classifier(const float* __restrict__ x,
        const float* __restrict__ w, const float* __restrict__ bias, float* __restrict__ out) {
    int b = blockIdx.x, lane = threadIdx.x;
    const float* xr = x + (long)b * T_ * D_;   // row 0 = cls token
    float logits[NC_];
#pragma unroll
    for (int c = 0; c < NC_; c++) {
        float s = 0.f;
        for (int d = lane; d < D_; d += 64) s += xr[d] * w[c * D_ + d];
#pragma unroll
        for (int off = 32; off; off >>= 1) s += __shfl_xor(s, off, 64);
        logits[c] = s + bias[c];
    }
    float mx = -1e30f;
#pragma unroll
    for (int c = 0; c < NC_; c++) mx = fmaxf(mx, logits[c]);
    float sum = 0.f;
#pragma unroll
    for (int c = 0; c < NC_; c++) { float e = expf(logits[c] - mx); logits[c] = e; sum += e; }
    if (lane == 0) {
        float inv = 1.f / sum;
#pragma unroll
        for (int c = 0; c < NC_; c++) out[(long)b * NC_ + c] = logits[c] * inv;
    }
}

// ---------------- host ----------------

extern "C" void kernel_launch(void* const* d_in, const int* in_sizes, int n_in,
                              void* d_out, int out_size, void* d_ws, size_t ws_size,
                              hipStream_t stream) {
    const float* images  = (const float*)d_in[0];
    const float* lin_w   = (const float*)d_in[1];
    const float* lin_b   = (const float*)d_in[2];
    const float* cls_tok = (const float*)d_in[3];
    const float* ln1_g   = (const float*)d_in[4];
    const float* ln1_b   = (const float*)d_in[5];
    const float* ln2_g   = (const float*)d_in[6];
    const float* ln2_b   = (const float*)d_in[7];
    const float* qw      = (const float*)d_in[8];
    const float* qb      = (const float*)d_in[9];
    const float* kw      = (const float*)d_in[10];
    const float* kb      = (const float*)d_in[11];
    const float* vw      = (const float*)d_in[12];
    const float* vb      = (const float*)d_in[13];
    const float* map_w   = (const float*)d_in[14];
    const float* map_b   = (const float*)d_in[15];
    const float* w1      = (const float*)d_in[16];
    const float* b1      = (const float*)d_in[17];
    const float* w2      = (const float*)d_in[18];
    const float* b2      = (const float*)d_in[19];
    const float* cls_w   = (const float*)d_in[20];
    const float* cls_b   = (const float*)d_in[21];

    char* wp = (char*)d_ws;
    auto alloc = [&](size_t bytes) { char* p = wp; wp += (bytes + 255) & ~(size_t)255; return p; };
    const long BT = (long)B_ * T_;                       // 25216

    // ~236 MB total (same as R4). +64-row pads absorb guard-free tile overreads.
    float* xf   = (float*)alloc(BT * D_ * 4);            // x (y in-place after LN2)
    bf16*  hb   = (bf16*) alloc(BT * D_ * 2);            // LN1/LN2 bf16 output
    bf16*  QKVh = (bf16*) alloc((BT + 64) * QKVW_ * 2);  // per-head fused Q|K|V
    bf16*  Pb   = (bf16*) alloc((BT + 64) * TP_ * 2);    // softmax probs (zero-padded)
    char*  scratch = alloc((long)CH0_ * M_ * 2);         // m1c (MLP) ∪ Rb (attn) ∪ patches
    bf16*  m1c  = (bf16*) scratch;
    bf16*  Rb   = (bf16*) scratch;                       // R = map @ P, per image [224] rows
    bf16*  patches = (bf16*)scratch;
    bf16*  wqkv = (bf16*)alloc((long)NH_ * QKVW_ * D_ * 2);
    float* qkvb = (float*)alloc((long)NH_ * QKVW_ * 4);
    bf16*  wmapP= (bf16*)alloc(((long)NH_ * T_ + 64) * TP_ * 2);
    bf16*  w1l  = (bf16*)alloc((long)M_ * D_ * 2);
    bf16*  w2l  = (bf16*)alloc((long)D_ * M_ * 2);
    bf16*  wlin = (bf16*)alloc((long)D_ * 256 * 2);

    auto conv = [&](const float* src, bf16* dst, long n) {
        k_f32_to_bf16v<<<1024, 256, 0, stream>>>(src, dst, n / 8);
    };

    conv(lin_w, wlin, (long)D_ * 256);
    {
        long tot = (long)B_ * 196 * 256;
        k_patchify<<<(int)((tot + 255) / 256), 256, 0, stream>>>(images, patches);
        k_cls_token<<<(B_ * D_ + 255) / 256, 256, 0, stream>>>(cls_tok, xf);
        // emb -> x[:,1:,:]
        k_gemm_bt<0><<<dim3(4, 2, B_), 256, 0, stream>>>(
            patches, 256, (long)196 * 256,
            wlin, 256, 0,
            xf + D_, D_, (long)T_ * D_,
            lin_b, nullptr, 0,
            196, D_, 256);
    }

    const float scale = 1.0f / 14.0f;
    const int lnGrid = (int)((BT + 3) / 4);

    for (int l = 0; l < L_; l++) {
        // stage this layer's weights
        k_prep_qkvw<<<(NH_ * QKVW_ * (D_ / 8) + 255) / 256, 256, 0, stream>>>(
            qw + (long)l * NH_ * D_ * D_, kw + (long)l * NH_ * D_ * D_,
            vw + (long)l * NH_ * D_ * D_, wqkv);
        k_prep_qkvb<<<(NH_ * QKVW_ + 255) / 256, 256, 0, stream>>>(
            qb + (long)l * NH_ * D_, kb + (long)l * NH_ * D_,
            vb + (long)l * NH_ * D_, qkvb);
        conv(w1 + (long)l * M_ * D_, w1l, (long)M_ * D_);
        conv(w2 + (long)l * D_ * M_, w2l, (long)D_ * M_);
        {
            int tot = NH_ * T_ * TP_;
            k_prep_map<<<(tot + 255) / 256, 256, 0, stream>>>(
                map_w + (long)l * T_ * T_ * NH_, wmapP);
        }

        k_ln<0><<<lnGrid, 256, 0, stream>>>(xf, ln1_g + l * D_, ln1_b + l * D_, hb, nullptr, (int)BT);

        for (int h = 0; h < NH_; h++) {
            // fused [Q|K|V] -> QKVh columns [0|512|1024]
            k_gemm_bt<1><<<dim3(12, 197, 1), 256, 0, stream>>>(
                hb, D_, 0, wqkv + (long)h * QKVW_ * D_, D_, 0,
                QKVh, QKVW_, 0, qkvb + (long)h * QKVW_, nullptr, 0,
                (int)BT, QKVW_, D_);

            // P = softmax(Q K^T * scale), fused, zero-padded to 224 cols
            k_attn_ssm<<<dim3(1, 4, B_), 256, 0, stream>>>(QKVh, Pb, scale);

            // R = map_h @ P   (per image, [197(224) x 224], K = token dim m)
            k_gemm_nn<0><<<dim3(2, 2, B_), 256, 0, stream>>>(
                wmapP + (long)h * T_ * TP_, TP_, 0,
                Pb, TP_, (long)T_ * TP_,
                Rb, TP_, (long)T_ * TP_, nullptr,
                T_, TP_, TP_);

            // x += R @ V   (+ map_b rowbias on first head); R cols >=197 are zero
            k_gemm_nn<1><<<dim3(4, 2, B_), 256, 0, stream>>>(
                Rb, TP_, (long)T_ * TP_,
                QKVh + 1024, QKVW_, (long)T_ * QKVW_,
                xf, D_, (long)T_ * D_,
                (h == 0) ? (map_b + (long)l * T_) : nullptr,
                T_, D_, TP_);
        }

        // y = LN2(x): bf16 -> hb, f32 in-place over xf (x is dead)
        k_ln<1><<<lnGrid, 256, 0, stream>>>(xf, ln2_g + l * D_, ln2_b + l * D_, hb, xf, (int)BT);

        // MLP in 2 row-chunks (12672 + 12544, both exact 128-multiples)
        long r0 = 0;
        for (int c = 0; c < 2; c++) {
            int rows = (c == 0) ? CH0_ : CH1_;
            k_gemm_bt<2><<<dim3(16, rows / 128, 1), 256, 0, stream>>>(
                hb + r0 * D_, D_, 0, w1l, D_, 0,
                m1c, M_, 0, b1 + (long)l * M_, nullptr, 0, rows, M_, D_);
            k_gemm_bt<3><<<dim3(4, rows / 128, 1), 256, 0, stream>>>(
                m1c, M_, 0, w2l, M_, 0,
                xf + r0 * D_, D_, 0, b2 + (long)l * D_, xf + r0 * D_, D_, rows, D_, M_);
            r0 += rows;
        }
    }

    k_classifier<<<B_, 64, 0, stream>>>(xf, cls_w, cls_b, (float*)d_out);
}

// Round 6
// 12458.973 us; speedup vs baseline: 2.4000x; 1.0830x over previous
//
#include <hip/hip_runtime.h>
#include <hip/hip_bf16.h>
#include <math.h>

#define B_   128
#define HW_  224
#define P_   16
#define D_   512
#define NH_  8
#define L_   6
#define M_   2048
#define NC_  10
#define GP_  14
#define T_   197
#define TP_  224    // padded T (multiple of 32): lda of P/R, K-dim of R/RV gemms
#define EPS_ 1e-5f
#define ZVW_ 1024   // fused per-head [Z|V] output width
#define CH0_ 12672  // MLP chunk 0 rows (99 blocks)
#define CH1_ 12544  // MLP chunk 1 rows (98 blocks)

typedef __hip_bfloat16 bf16;
typedef __attribute__((ext_vector_type(8))) __bf16 bf16x8;
typedef __attribute__((ext_vector_type(4))) float  f32x4;

// async global->LDS, 16B per lane. LDS dest = wave-uniform base + lane*16.
__device__ __forceinline__ void gload16(const void* g, void* l) {
    __builtin_amdgcn_global_load_lds(
        (const __attribute__((address_space(1))) void*)g,
        (__attribute__((address_space(3))) void*)l, 16, 0, 0);
}

// ---------------- elementwise / prep helpers ----------------

__global__ void k_f32_to_bf16v(const float* __restrict__ in, bf16* __restrict__ out, long n8) {
    long stride = (long)gridDim.x * blockDim.x;
    for (long i = (long)blockIdx.x * blockDim.x + threadIdx.x; i < n8; i += stride) {
        float4 a = ((const float4*)in)[i * 2], b = ((const float4*)in)[i * 2 + 1];
        union { uint4 u; bf16 h[8]; } r;
        r.h[0] = __float2bfloat16(a.x); r.h[1] = __float2bfloat16(a.y);
        r.h[2] = __float2bfloat16(a.z); r.h[3] = __float2bfloat16(a.w);
        r.h[4] = __float2bfloat16(b.x); r.h[5] = __float2bfloat16(b.y);
        r.h[6] = __float2bfloat16(b.z); r.h[7] = __float2bfloat16(b.w);
        ((uint4*)out)[i] = r.u;
    }
}

// vw_l [h][e][d] f32 -> wzv[h][512+e][d] bf16 (V half of the fused [H|Wv] B matrix)
__global__ void k_prep_wv(const float* __restrict__ vw, bf16* __restrict__ wzv) {
    int idx = blockIdx.x * blockDim.x + threadIdx.x;   // [h][e][d8]
    if (idx >= NH_ * D_ * (D_ / 8)) return;
    int d8 = idx & 63;
    int e  = (idx >> 6) & 511;
    int h  = idx >> 15;
    long so = ((long)(h * D_ + e)) * D_ + d8 * 8;
    float4 a = *(const float4*)(vw + so), b = *(const float4*)(vw + so + 4);
    union { uint4 u; bf16 hh[8]; } rr;
    rr.hh[0] = __float2bfloat16(a.x); rr.hh[1] = __float2bfloat16(a.y);
    rr.hh[2] = __float2bfloat16(a.z); rr.hh[3] = __float2bfloat16(a.w);
    rr.hh[4] = __float2bfloat16(b.x); rr.hh[5] = __float2bfloat16(b.y);
    rr.hh[6] = __float2bfloat16(b.z); rr.hh[7] = __float2bfloat16(b.w);
    ((uint4*)wzv)[((long)(h * ZVW_ + 512 + e)) * 64 + d8] = rr.u;
}

// bias vector: out[h][j] = (j<512) ? u[j] = sum_e kw[h][e][j]*qb[h][e]  : vb[h][j-512]
__global__ void k_prep_ub(const float* __restrict__ kw, const float* __restrict__ qb,
                          const float* __restrict__ vb, float* __restrict__ out) {
    int idx = blockIdx.x * blockDim.x + threadIdx.x;
    if (idx >= NH_ * ZVW_) return;
    int j = idx & (ZVW_ - 1), h = idx >> 10;
    if (j < 512) {
        const float* kwh = kw + (long)h * D_ * D_ + j;
        const float* qbh = qb + h * D_;
        float s = 0.f;
        for (int e = 0; e < D_; e++) s += kwh[(long)e * D_] * qbh[e];
        out[idx] = s;
    } else {
        out[idx] = vb[h * D_ + (j - 512)];
    }
}

__global__ void k_patchify(const float* __restrict__ img, bf16* __restrict__ patches) {
    long idx = (long)blockIdx.x * blockDim.x + threadIdx.x;
    long total = (long)B_ * 196 * 256;
    if (idx >= total) return;
    int q = (int)(idx & 255);
    int p = (int)((idx >> 8) % 196);
    int b = (int)(idx / (196 * 256));
    int gy = p / GP_, gx = p % GP_;
    int py = q >> 4,  px = q & 15;
    patches[idx] = __float2bfloat16(img[((long)b * HW_ + gy * P_ + py) * HW_ + gx * P_ + px]);
}

__global__ void k_cls_token(const float* __restrict__ tok, float* __restrict__ x) {
    int i = blockIdx.x * blockDim.x + threadIdx.x;
    if (i < B_ * D_) {
        int b = i >> 9, d = i & 511;
        x[(long)b * T_ * D_ + d] = tok[d];
    }
}

// map_w[l] is [T][T*NH]; produce per-head zero-K-padded A: out[h][t][s] (lda=TP_)
__global__ void k_prep_map(const float* __restrict__ in, bf16* __restrict__ out) {
    int idx = blockIdx.x * blockDim.x + threadIdx.x;
    int total = NH_ * T_ * TP_;
    if (idx >= total) return;
    int s = idx % TP_;
    int t = (idx / TP_) % T_;
    int h = idx / (TP_ * T_);
    float v = (s < T_) ? in[t * (T_ * NH_) + h * T_ + s] : 0.f;
    out[idx] = __float2bfloat16(v);
}

// ---------------- LayerNorm (one wave per row of 512) ----------------

template<int WRITE_Y>
__global__ __launch_bounds__(256) void k_ln(const float* x,
        const float* __restrict__ g, const float* __restrict__ bb,
        bf16* __restrict__ obf, float* of, int rows) {
    int wid = blockIdx.x * 4 + (threadIdx.x >> 6);
    if (wid >= rows) return;
    int lane = threadIdx.x & 63;
    const float* xr = x + (long)wid * D_;
    float v[8];
    float s = 0.f;
#pragma unroll
    for (int i = 0; i < 8; i++) { v[i] = xr[i * 64 + lane]; s += v[i]; }
#pragma unroll
    for (int off = 32; off; off >>= 1) s += __shfl_xor(s, off, 64);
    float mean = s * (1.f / D_);
    float sq = 0.f;
#pragma unroll
    for (int i = 0; i < 8; i++) { float d = v[i] - mean; sq += d * d; }
#pragma unroll
    for (int off = 32; off; off >>= 1) sq += __shfl_xor(sq, off, 64);
    float inv = rsqrtf(sq * (1.f / D_) + EPS_);
#pragma unroll
    for (int i = 0; i < 8; i++) {
        int d = i * 64 + lane;
        float val = (v[i] - mean) * inv * g[d] + bb[d];
        obf[(long)wid * D_ + d] = __float2bfloat16(val);
        if (WRITE_Y) of[(long)wid * D_ + d] = val;
    }
}

// ---------------- fused S = Q' K'^T (scaled) + row-softmax -> P (bf16, zero-padded) ----
// Q' = Z (per-head, ldq), K' = hb (shared, ldk). Block = (image z, 64 q-rows).

__global__ __launch_bounds__(256) void k_attn_ssm(
        const bf16* __restrict__ Qp, long ldq,
        const bf16* __restrict__ Kp, long ldk,
        bf16* __restrict__ Pm, float scale) {
    __shared__ __align__(16) bf16 Qs[64][32];
    __shared__ __align__(16) bf16 Ks[256][32];
    int z = blockIdx.z;
    int q0 = blockIdx.y * 64;
    int tid = threadIdx.x;
    int wv = tid >> 6, lane = tid & 63;
    int rA = tid >> 2, pA = (tid & 3) * 8;

    const bf16* Qb = Qp + ((long)z * T_ + q0 + rA) * ldq + pA;
    const bf16* Kb = Kp + ((long)z * T_ + rA) * ldk + pA;
    char* lQ = (char*)Qs + (wv * 16) * 64;

    f32x4 acc[14];
#pragma unroll
    for (int f = 0; f < 14; f++) acc[f] = (f32x4){0.f, 0.f, 0.f, 0.f};

    for (int kt = 0; kt < 16; kt++) {
        long k0 = (long)kt * 32;
        gload16(Qb + k0, lQ);
#pragma unroll
        for (int p = 0; p < 4; p++)
            gload16(Kb + ((long)p * 64) * ldk + k0, (char*)Ks + (p * 64 + wv * 16) * 64);
        __syncthreads();
        bf16x8 af = *(const bf16x8*)&Qs[wv * 16 + (lane & 15)][(lane >> 4) * 8];
#pragma unroll
        for (int f = 0; f < 14; f++) {
            bf16x8 bfr = *(const bf16x8*)&Ks[f * 16 + (lane & 15)][(lane >> 4) * 8];
            acc[f] = __builtin_amdgcn_mfma_f32_16x16x32_bf16(af, bfr, acc[f], 0, 0, 0);
        }
        __syncthreads();
    }

    int c1 = lane & 15, grp = lane >> 4;
    float mx[4] = {-1e30f, -1e30f, -1e30f, -1e30f};
    float sm[4] = {0.f, 0.f, 0.f, 0.f};
#pragma unroll
    for (int f = 0; f < 14; f++) {
        int col = f * 16 + c1;
        bool val = (col < T_);
#pragma unroll
        for (int r = 0; r < 4; r++) {
            float v = val ? acc[f][r] * scale : -1e30f;
            acc[f][r] = v;
            mx[r] = fmaxf(mx[r], v);
        }
    }
#pragma unroll
    for (int r = 0; r < 4; r++)
#pragma unroll
        for (int off = 1; off < 16; off <<= 1) mx[r] = fmaxf(mx[r], __shfl_xor(mx[r], off, 64));
#pragma unroll
    for (int f = 0; f < 14; f++) {
        int col = f * 16 + c1;
        bool val = (col < T_);
#pragma unroll
        for (int r = 0; r < 4; r++) {
            float e = val ? expf(acc[f][r] - mx[r]) : 0.f;
            acc[f][r] = e;
            sm[r] += e;
        }
    }
#pragma unroll
    for (int r = 0; r < 4; r++) {
#pragma unroll
        for (int off = 1; off < 16; off <<= 1) sm[r] += __shfl_xor(sm[r], off, 64);
        sm[r] = 1.f / sm[r];
    }
#pragma unroll
    for (int f = 0; f < 14; f++)
#pragma unroll
        for (int r = 0; r < 4; r++) {
            int qi = q0 + wv * 16 + grp * 4 + r;
            if (qi < T_)
                Pm[((long)z * T_ + qi) * TP_ + f * 16 + c1] = __float2bfloat16(acc[f][r] * sm[r]);
        }
}

// ---------------- GEMM kernels ----------------

__device__ __forceinline__ float geluf(float v) {
    return 0.5f * v * (1.f + erff(v * 0.70710678118654752f));
}

// C[M,N] = A[M,K] @ B[N,K]^T.  Guard-free loads; stores guarded. K % 32 == 0.
// MODE 0: f32 store (v + bias?)       MODE 1: bf16 store (v + bias)
// MODE 2: bf16 store gelu(v + bias)   MODE 3: f32 store (v + bias + res)  (res may alias C)
template<int MODE>
__global__ __launch_bounds__(256) void k_gemm_bt(
        const bf16* __restrict__ A, long lda, long bsA,
        const bf16* __restrict__ Bw, long ldb, long bsB,
        void* __restrict__ Cp, long ldc, long bsC,
        const float* __restrict__ bias,
        const float* res, long ldres,
        int Mt, int Nt, int Kt) {
    __shared__ __align__(16) bf16 As[128][32];
    __shared__ __align__(16) bf16 Bs[128][32];
    int bz = blockIdx.z;
    A  += (long)bz * bsA;
    Bw += (long)bz * bsB;
    int m0 = blockIdx.y * 128, n0 = blockIdx.x * 128;
    int tid = threadIdx.x;
    int wv = tid >> 6, lane = tid & 63;
    int wm = (wv >> 1) * 64, wn = (wv & 1) * 64;
    int lrow = lane & 15, koff = (lane >> 4) * 8;

    int rA = tid >> 2, pA = (tid & 3) * 8;          // 64 rows per 256-thread pass
    const bf16* gA0 = A  + (long)(m0 + rA) * lda + pA;
    const bf16* gA1 = A  + (long)(m0 + 64 + rA) * lda + pA;
    const bf16* gB0 = Bw + (long)(n0 + rA) * ldb + pA;
    const bf16* gB1 = Bw + (long)(n0 + 64 + rA) * ldb + pA;
    char* lA0 = (char*)As + (wv * 64) * 16;         // wave-uniform LDS bases
    char* lA1 = (char*)As + (256 + wv * 64) * 16;
    char* lB0 = (char*)Bs + (wv * 64) * 16;
    char* lB1 = (char*)Bs + (256 + wv * 64) * 16;

    f32x4 acc[4][4];
#pragma unroll
    for (int i = 0; i < 4; i++)
#pragma unroll
        for (int j = 0; j < 4; j++) acc[i][j] = (f32x4){0.f, 0.f, 0.f, 0.f};

    int kTiles = Kt >> 5;
    for (int kt = 0; kt < kTiles; kt++) {
        long k0 = (long)kt << 5;
        gload16(gA0 + k0, lA0);
        gload16(gA1 + k0, lA1);
        gload16(gB0 + k0, lB0);
        gload16(gB1 + k0, lB1);
        __syncthreads();
        bf16x8 af[4], bfr[4];
#pragma unroll
        for (int mi = 0; mi < 4; mi++) af[mi]  = *(const bf16x8*)&As[wm + mi * 16 + lrow][koff];
#pragma unroll
        for (int ni = 0; ni < 4; ni++) bfr[ni] = *(const bf16x8*)&Bs[wn + ni * 16 + lrow][koff];
#pragma unroll
        for (int mi = 0; mi < 4; mi++)
#pragma unroll
            for (int ni = 0; ni < 4; ni++)
                acc[mi][ni] = __builtin_amdgcn_mfma_f32_16x16x32_bf16(af[mi], bfr[ni], acc[mi][ni], 0, 0, 0);
        __syncthreads();
    }

    int r4 = (lane >> 4) * 4, c1 = lane & 15;
#pragma unroll
    for (int mi = 0; mi < 4; mi++) {
#pragma unroll
        for (int r = 0; r < 4; r++) {
            int row = m0 + wm + mi * 16 + r4 + r;
            if (row >= Mt) continue;
#pragma unroll
            for (int ni = 0; ni < 4; ni++) {
                int col = n0 + wn + ni * 16 + c1;
                if (col >= Nt) continue;
                float v = acc[mi][ni][r];
                if (bias) v += bias[col];
                long cidx = (long)bz * bsC + (long)row * ldc + col;
                if (MODE == 0)      ((float*)Cp)[cidx] = v;
                else if (MODE == 1) ((bf16*)Cp)[cidx]  = __float2bfloat16(v);
                else if (MODE == 2) ((bf16*)Cp)[cidx]  = __float2bfloat16(geluf(v));
                else                ((float*)Cp)[cidx] = v + res[(long)row * ldres + col];
            }
        }
    }
}

// C[M,N] (op)= A[M,K] @ B[K,N], B row-major KxN. Guard-free loads; K % 32 == 0
// (caller zero-pads the ragged K on the A side). Stores guarded.
// MODE 0: bf16 store.   MODE 1: f32 accumulate C += v + rowbias[row] (rowbias optional)
template<int MODE>
__global__ __launch_bounds__(256) void k_gemm_nn(
        const bf16* __restrict__ A, long lda, long bsA,
        const bf16* __restrict__ Bw, long ldb, long bsB,
        void* __restrict__ Cp, long ldc, long bsC,
        const float* __restrict__ rowbias,
        int Mt, int Nt, int Kt) {
    __shared__ __align__(16) bf16 As[128][32];
    __shared__ __align__(16) bf16 Bs[128][32];
    int bz = blockIdx.z;
    A  += (long)bz * bsA;
    Bw += (long)bz * bsB;
    int m0 = blockIdx.y * 128, n0 = blockIdx.x * 128;
    int tid = threadIdx.x;
    int wv = tid >> 6, lane = tid & 63;
    int wm = (wv >> 1) * 64, wn = (wv & 1) * 64;
    int lrow = lane & 15, koff = (lane >> 4) * 8;

    int rA = tid >> 2, pA = (tid & 3) * 8;
    const bf16* gA0 = A + (long)(m0 + rA) * lda + pA;
    const bf16* gA1 = A + (long)(m0 + 64 + rA) * lda + pA;
    char* lA0 = (char*)As + (wv * 64) * 16;
    char* lA1 = (char*)As + (256 + wv * 64) * 16;
    int bk = tid & 31, bg = tid >> 5;               // B transpose staging coords

    f32x4 acc[4][4];
#pragma unroll
    for (int i = 0; i < 4; i++)
#pragma unroll
        for (int j = 0; j < 4; j++) acc[i][j] = (f32x4){0.f, 0.f, 0.f, 0.f};

    int kTiles = Kt >> 5;
    for (int kt = 0; kt < kTiles; kt++) {
        long k0 = (long)kt << 5;
        gload16(gA0 + k0, lA0);
        gload16(gA1 + k0, lA1);
#pragma unroll
        for (int i = 0; i < 2; i++) {
            int g = bg + 8 * i;
            uint4 v = *(const uint4*)(Bw + (k0 + bk) * ldb + n0 + g * 8);
            const bf16* pv = (const bf16*)&v;
#pragma unroll
            for (int j = 0; j < 8; j++) Bs[g * 8 + j][bk] = pv[j];
        }
        __syncthreads();
        bf16x8 af[4], bfr[4];
#pragma unroll
        for (int mi = 0; mi < 4; mi++) af[mi]  = *(const bf16x8*)&As[wm + mi * 16 + lrow][koff];
#pragma unroll
        for (int ni = 0; ni < 4; ni++) bfr[ni] = *(const bf16x8*)&Bs[wn + ni * 16 + lrow][koff];
#pragma unroll
        for (int mi = 0; mi < 4; mi++)
#pragma unroll
            for (int ni = 0; ni < 4; ni++)
                acc[mi][ni] = __builtin_amdgcn_mfma_f32_16x16x32_bf16(af[mi], bfr[ni], acc[mi][ni], 0, 0, 0);
        __syncthreads();
    }

    int r4 = (lane >> 4) * 4, c1 = lane & 15;
#pragma unroll
    for (int mi = 0; mi < 4; mi++) {
#pragma unroll
        for (int r = 0; r < 4; r++) {
            int row = m0 + wm + mi * 16 + r4 + r;
            if (row >= Mt) continue;
#pragma unroll
            for (int ni = 0; ni < 4; ni++) {
                int col = n0 + wn + ni * 16 + c1;
                if (col >= Nt) continue;
                float v = acc[mi][ni][r];
                long cidx = (long)bz * bsC + (long)row * ldc + col;
                if (MODE == 0) {
                    ((bf16*)Cp)[cidx] = __float2bfloat16(v);
                } else {
                    if (rowbias) v += rowbias[row];
                    ((float*)Cp)[cidx] += v;
                }
            }
        }
    }
}

// C[M,N] = A^T @ B. A [K][M] row-major, B [K][N] row-major, bf16 store. K%32==0.
__global__ __launch_bounds__(256) void k_gemm_tn(
        const bf16* __restrict__ A, long lda, long bsA,
        const bf16* __restrict__ Bw, long ldb, long bsB,
        bf16* __restrict__ Cp, long ldc, long bsC,
        int Mt, int Nt, int Kt) {
    __shared__ __align__(16) bf16 As[128][32];
    __shared__ __align__(16) bf16 Bs[128][32];
    int bz = blockIdx.z;
    A  += (long)bz * bsA;
    Bw += (long)bz * bsB;
    int m0 = blockIdx.y * 128, n0 = blockIdx.x * 128;
    int tid = threadIdx.x;
    int wv = tid >> 6, lane = tid & 63;
    int wm = (wv >> 1) * 64, wn = (wv & 1) * 64;
    int lrow = lane & 15, koff = (lane >> 4) * 8;
    int bk = tid & 31, bg = tid >> 5;

    f32x4 acc[4][4];
#pragma unroll
    for (int i = 0; i < 4; i++)
#pragma unroll
        for (int j = 0; j < 4; j++) acc[i][j] = (f32x4){0.f, 0.f, 0.f, 0.f};

    int kTiles = Kt >> 5;
    for (int kt = 0; kt < kTiles; kt++) {
        long k0 = (long)kt << 5;
#pragma unroll
        for (int i = 0; i < 2; i++) {
            int g = bg + 8 * i;
            uint4 va = *(const uint4*)(A + (k0 + bk) * lda + m0 + g * 8);
            const bf16* pa = (const bf16*)&va;
#pragma unroll
            for (int j = 0; j < 8; j++) As[g * 8 + j][bk] = pa[j];
            uint4 vb = *(const uint4*)(Bw + (k0 + bk) * ldb + n0 + g * 8);
            const bf16* pb = (const bf16*)&vb;
#pragma unroll
            for (int j = 0; j < 8; j++) Bs[g * 8 + j][bk] = pb[j];
        }
        __syncthreads();
        bf16x8 af[4], bfr[4];
#pragma unroll
        for (int mi = 0; mi < 4; mi++) af[mi]  = *(const bf16x8*)&As[wm + mi * 16 + lrow][koff];
#pragma unroll
        for (int ni = 0; ni < 4; ni++) bfr[ni] = *(const bf16x8*)&Bs[wn + ni * 16 + lrow][koff];
#pragma unroll
        for (int mi = 0; mi < 4; mi++)
#pragma unroll
            for (int ni = 0; ni < 4; ni++)
                acc[mi][ni] = __builtin_amdgcn_mfma_f32_16x16x32_bf16(af[mi], bfr[ni], acc[mi][ni], 0, 0, 0);
        __syncthreads();
    }

    int r4 = (lane >> 4) * 4, c1 = lane & 15;
#pragma unroll
    for (int mi = 0; mi < 4; mi++) {
#pragma unroll
        for (int r = 0; r < 4; r++) {
            int row = m0 + wm + mi * 16 + r4 + r;
            if (row >= Mt) continue;
#pragma unroll
            for (int ni = 0; ni < 4; ni++) {
                int col = n0 + wn + ni * 16 + c1;
                if (col >= Nt) continue;
                Cp[(long)bz * bsC + (long)row * ldc + col] = __float2bfloat16(acc[mi][ni][r]);
            }
        }
    }
}

// ---------------- classifier + softmax ----------------

__global__ __launch_bounds__(64) void k_classifier(const float* __restrict__ x,
        const float* __restrict__ w, const float* __restrict__ bias, float* __restrict__ out) {
    int b = blockIdx.x, lane = threadIdx.x;
    const float* xr = x + (long)b * T_ * D_;   // row 0 = cls token
    float logits[NC_];
#pragma unroll
    for (int c = 0; c < NC_; c++) {
        float s = 0.f;
        for (int d = lane; d < D_; d += 64) s += xr[d] * w[c * D_ + d];
#pragma unroll
        for (int off = 32; off; off >>= 1) s += __shfl_xor(s, off, 64);
        logits[c] = s + bias[c];
    }
    float mx = -1e30f;
#pragma unroll
    for (int c = 0; c < NC_; c++) mx = fmaxf(mx, logits[c]);
    float sum = 0.f;
#pragma unroll
    for (int c = 0; c < NC_; c++) { float e = expf(logits[c] - mx); logits[c] = e; sum += e; }
    if (lane == 0) {
        float inv = 1.f / sum;
#pragma unroll
        for (int c = 0; c < NC_; c++) out[(long)b * NC_ + c] = logits[c] * inv;
    }
}

// ---------------- host ----------------

extern "C" void kernel_launch(void* const* d_in, const int* in_sizes, int n_in,
                              void* d_out, int out_size, void* d_ws, size_t ws_size,
                              hipStream_t stream) {
    const float* images  = (const float*)d_in[0];
    const float* lin_w   = (const float*)d_in[1];
    const float* lin_b   = (const float*)d_in[2];
    const float* cls_tok = (const float*)d_in[3];
    const float* ln1_g   = (const float*)d_in[4];
    const float* ln1_b   = (const float*)d_in[5];
    const float* ln2_g   = (const float*)d_in[6];
    const float* ln2_b   = (const float*)d_in[7];
    const float* qw      = (const float*)d_in[8];
    const float* qb      = (const float*)d_in[9];
    const float* kw      = (const float*)d_in[10];
    const float* kb      = (const float*)d_in[11];
    const float* vw      = (const float*)d_in[12];
    const float* vb      = (const float*)d_in[13];
    const float* map_w   = (const float*)d_in[14];
    const float* map_b   = (const float*)d_in[15];
    const float* w1      = (const float*)d_in[16];
    const float* b1      = (const float*)d_in[17];
    const float* w2      = (const float*)d_in[18];
    const float* b2      = (const float*)d_in[19];
    const float* cls_w   = (const float*)d_in[20];
    const float* cls_b   = (const float*)d_in[21];

    char* wp = (char*)d_ws;
    auto alloc = [&](size_t bytes) { char* p = wp; wp += (bytes + 255) & ~(size_t)255; return p; };
    const long BT = (long)B_ * T_;                       // 25216

    // ~206 MB total. +64-row pads absorb guard-free tile overreads (finite poison).
    float* xf   = (float*)alloc(BT * D_ * 4);            // x (y in-place after LN2)
    bf16*  hb   = (bf16*) alloc(BT * D_ * 2);            // LN1/LN2 bf16 output (also attn K)
    bf16*  ZVh  = (bf16*) alloc((BT + 64) * ZVW_ * 2);   // per-head fused Z|V
    bf16*  Pb   = (bf16*) alloc((BT + 64) * TP_ * 2);    // softmax probs (zero-padded)
    char*  scratch = alloc((long)CH0_ * M_ * 2);         // m1c ∪ Rb ∪ patches ∪ wqb/wkb
    bf16*  m1c  = (bf16*) scratch;
    bf16*  Rb   = (bf16*) scratch;                       // R = map @ P, per image
    bf16*  patches = (bf16*)scratch;
    bf16*  wqb  = (bf16*) scratch;                                   // prep-time only
    bf16*  wkb  = (bf16*)(scratch + (long)NH_ * D_ * D_ * 2);        // prep-time only
    bf16*  wzv  = (bf16*)alloc((long)NH_ * ZVW_ * D_ * 2);   // [h][ H(512) ; Wv(512) ][512]
    float* zvb  = (float*)alloc((long)NH_ * ZVW_ * 4);       // [h][ u ; vb ]
    bf16*  wmapP= (bf16*)alloc(((long)NH_ * T_ + 64) * TP_ * 2);
    bf16*  w1l  = (bf16*)alloc((long)M_ * D_ * 2);
    bf16*  w2l  = (bf16*)alloc((long)D_ * M_ * 2);
    bf16*  wlin = (bf16*)alloc((long)D_ * 256 * 2);

    auto conv = [&](const float* src, bf16* dst, long n) {
        k_f32_to_bf16v<<<1024, 256, 0, stream>>>(src, dst, n / 8);
    };

    conv(lin_w, wlin, (long)D_ * 256);
    {
        long tot = (long)B_ * 196 * 256;
        k_patchify<<<(int)((tot + 255) / 256), 256, 0, stream>>>(images, patches);
        k_cls_token<<<(B_ * D_ + 255) / 256, 256, 0, stream>>>(cls_tok, xf);
        // emb -> x[:,1:,:]
        k_gemm_bt<0><<<dim3(4, 2, B_), 256, 0, stream>>>(
            patches, 256, (long)196 * 256,
            wlin, 256, 0,
            xf + D_, D_, (long)T_ * D_,
            lin_b, nullptr, 0,
            196, D_, 256);
    }

    const float scale = 1.0f / 14.0f;
    const int lnGrid = (int)((BT + 3) / 4);

    for (int l = 0; l < L_; l++) {
        // ---- per-layer weight prep ----
        // H_h = Wk_h^T @ Wq_h  (softmax row-invariance absorbs the other bias terms)
        conv(qw + (long)l * NH_ * D_ * D_, wqb, (long)NH_ * D_ * D_);
        conv(kw + (long)l * NH_ * D_ * D_, wkb, (long)NH_ * D_ * D_);
        k_gemm_tn<<<dim3(4, 4, NH_), 256, 0, stream>>>(
            wkb, D_, (long)D_ * D_,
            wqb, D_, (long)D_ * D_,
            wzv, D_, (long)ZVW_ * D_,          // rows 0..511 of each head's B
            D_, D_, D_);
        k_prep_wv<<<(NH_ * D_ * (D_ / 8) + 255) / 256, 256, 0, stream>>>(
            vw + (long)l * NH_ * D_ * D_, wzv);
        k_prep_ub<<<(NH_ * ZVW_ + 255) / 256, 256, 0, stream>>>(
            kw + (long)l * NH_ * D_ * D_, qb + (long)l * NH_ * D_,
            vb + (long)l * NH_ * D_, zvb);
        conv(w1 + (long)l * M_ * D_, w1l, (long)M_ * D_);
        conv(w2 + (long)l * D_ * M_, w2l, (long)D_ * M_);
        k_prep_map<<<(NH_ * T_ * TP_ + 255) / 256, 256, 0, stream>>>(
            map_w + (long)l * T_ * T_ * NH_, wmapP);

        k_ln<0><<<lnGrid, 256, 0, stream>>>(xf, ln1_g + l * D_, ln1_b + l * D_, hb, nullptr, (int)BT);

        for (int h = 0; h < NH_; h++) {
            // fused [Z|V] = hb @ [H_h; Wv_h]^T + [u_h; vb_h]
            k_gemm_bt<1><<<dim3(8, 197, 1), 256, 0, stream>>>(
                hb, D_, 0, wzv + (long)h * ZVW_ * D_, D_, 0,
                ZVh, ZVW_, 0, zvb + (long)h * ZVW_, nullptr, 0,
                (int)BT, ZVW_, D_);

            // P = softmax(Z hb^T * scale), fused, zero-padded to 224 cols
            k_attn_ssm<<<dim3(1, 4, B_), 256, 0, stream>>>(
                ZVh, ZVW_, hb, D_, Pb, scale);

            // R = map_h @ P   (per image)
            k_gemm_nn<0><<<dim3(2, 2, B_), 256, 0, stream>>>(
                wmapP + (long)h * T_ * TP_, TP_, 0,
                Pb, TP_, (long)T_ * TP_,
                Rb, TP_, (long)T_ * TP_, nullptr,
                T_, TP_, TP_);

            // x += R @ V   (+ map_b rowbias on first head); R cols >=197 are zero
            k_gemm_nn<1><<<dim3(4, 2, B_), 256, 0, stream>>>(
                Rb, TP_, (long)T_ * TP_,
                ZVh + 512, ZVW_, (long)T_ * ZVW_,
                xf, D_, (long)T_ * D_,
                (h == 0) ? (map_b + (long)l * T_) : nullptr,
                T_, D_, TP_);
        }

        // y = LN2(x): bf16 -> hb, f32 in-place over xf (x is dead)
        k_ln<1><<<lnGrid, 256, 0, stream>>>(xf, ln2_g + l * D_, ln2_b + l * D_, hb, xf, (int)BT);

        // MLP in 2 row-chunks (12672 + 12544, both exact 128-multiples)
        long r0 = 0;
        for (int c = 0; c < 2; c++) {
            int rows = (c == 0) ? CH0_ : CH1_;
            k_gemm_bt<2><<<dim3(16, rows / 128, 1), 256, 0, stream>>>(
                hb + r0 * D_, D_, 0, w1l, D_, 0,
                m1c, M_, 0, b1 + (long)l * M_, nullptr, 0, rows, M_, D_);
            k_gemm_bt<3><<<dim3(4, rows / 128, 1), 256, 0, stream>>>(
                m1c, M_, 0, w2l, M_, 0,
                xf + r0 * D_, D_, 0, b2 + (long)l * D_, xf + r0 * D_, D_, rows, D_, M_);
            r0 += rows;
        }
    }

    k_classifier<<<B_, 64, 0, stream>>>(xf, cls_w, cls_b, (float*)d_out);
}